// Round 7
// baseline (156.865 us; speedup 1.0000x reference)
//
#include <hip/hip_runtime.h>
#include <math.h>

#define N_TOK 8192
#define C_DIM 128
#define NHD   8
#define HDIM  16
#define NR    1024
#define EPSV  1e-5f
#define QK_SCALE 0.25f
#define QK_L2E  0.36067376f   /* 0.25 * log2(e) */

typedef __attribute__((ext_vector_type(8))) short short8;
typedef __attribute__((ext_vector_type(4))) float f32x4;

__device__ __forceinline__ float gelu_f(float v) {
    return 0.5f * v * (1.0f + erff(v * 0.70710678118654752f));
}
__device__ __forceinline__ float uaf(unsigned int u) {
    union { unsigned int u; float f; } x; x.u = u; return x.f;
}
__device__ __forceinline__ short f2b(float v) {
    union { float f; unsigned int u; } x; x.f = v;
    unsigned int r = x.u + 0x7fffu + ((x.u >> 16) & 1u);
    return (short)(r >> 16);
}
__device__ __forceinline__ void ld16bf(const short* p, float* d) {
    uint4 a = *(const uint4*)p;
    uint4 b = *(const uint4*)(p + 8);
    d[0]  = uaf(a.x << 16); d[1]  = uaf(a.x & 0xffff0000u);
    d[2]  = uaf(a.y << 16); d[3]  = uaf(a.y & 0xffff0000u);
    d[4]  = uaf(a.z << 16); d[5]  = uaf(a.z & 0xffff0000u);
    d[6]  = uaf(a.w << 16); d[7]  = uaf(a.w & 0xffff0000u);
    d[8]  = uaf(b.x << 16); d[9]  = uaf(b.x & 0xffff0000u);
    d[10] = uaf(b.y << 16); d[11] = uaf(b.y & 0xffff0000u);
    d[12] = uaf(b.z << 16); d[13] = uaf(b.z & 0xffff0000u);
    d[14] = uaf(b.w << 16); d[15] = uaf(b.w & 0xffff0000u);
}

struct CvtDesc { const float* src; short* dst; int n; int pad; };
struct CvtArgs { CvtDesc d[10]; };

// ------- fused: weight cvt (blocks 128..167) + transpose+LN1 (blocks 0..127) --------
__global__ __launch_bounds__(256) void xlncvt_k(const float* __restrict__ x,
                                                const float* __restrict__ g1, const float* __restrict__ b1,
                                                const float* __restrict__ g2, const float* __restrict__ b2,
                                                float* __restrict__ xt,
                                                short* __restrict__ o1, short* __restrict__ o2,
                                                CvtArgs ca) {
    __shared__ float tile[64][130];
    int t = threadIdx.x;
    if (blockIdx.x >= 128) {
        int bid = blockIdx.x - 128;   // 0..39
#pragma unroll 1
        for (int d = 0; d < 10; ++d) {
            CvtDesc dd = ca.d[d];
            for (int i = bid * 256 + t; i < dd.n; i += 40 * 256)
                dd.dst[i] = f2b(dd.src[i]);
        }
        return;
    }
    int n0 = blockIdx.x * 64;
#pragma unroll
    for (int k = 0; k < 32; ++k) {
        int flat = t + k * 256;
        int n = flat & 63, c = flat >> 6;
        tile[n][c] = x[(size_t)c * N_TOK + n0 + n];
    }
    __syncthreads();
    int tl = t >> 2, qt = t & 3;
    float v[32];
    float s = 0.f, sq = 0.f;
#pragma unroll
    for (int i = 0; i < 32; ++i) {
        v[i] = tile[tl][qt * 32 + i];
        s += v[i]; sq += v[i] * v[i];
    }
    s += __shfl_xor(s, 1);  s += __shfl_xor(s, 2);
    sq += __shfl_xor(sq, 1); sq += __shfl_xor(sq, 2);
    float m = s * (1.0f / 128.0f);
    float var = sq * (1.0f / 128.0f) - m * m;
    float rs = rsqrtf(var + EPSV);
    int tok = n0 + tl, cb = qt * 32;
    float* xtp = xt + (size_t)tok * C_DIM + cb;
    short* oA = o1 + (size_t)tok * C_DIM + cb;
    short* oG = o2 + (size_t)tok * C_DIM + cb;
#pragma unroll
    for (int i = 0; i < 32; ++i) {
        float hn = (v[i] - m) * rs;
        xtp[i] = v[i];
        oA[i] = f2b(hn * g1[cb + i] + b1[cb + i]);
        oG[i] = f2b(hn * g2[cb + i] + b2[cb + i]);
    }
}

// ---------------- second LN, paired across branches ----------------
__global__ __launch_bounds__(256) void ln2_pair_k(const float* __restrict__ in0,
                                                  const float* __restrict__ g0, const float* __restrict__ b0,
                                                  short* __restrict__ o0,
                                                  const float* __restrict__ in1,
                                                  const float* __restrict__ g1, const float* __restrict__ b1,
                                                  short* __restrict__ o1) {
    int blk = blockIdx.x;
    bool sel = blk >= 2048;
    blk &= 2047;
    const float* in = sel ? in1 : in0;
    const float* g  = sel ? g1 : g0;
    const float* b  = sel ? b1 : b0;
    short* o        = sel ? o1 : o0;
    int lane = threadIdx.x & 63;
    int n = blk * 4 + (threadIdx.x >> 6);
    float v0 = in[(size_t)n * C_DIM + lane];
    float v1 = in[(size_t)n * C_DIM + 64 + lane];
    float s = v0 + v1, sq = v0 * v0 + v1 * v1;
#pragma unroll
    for (int off = 32; off >= 1; off >>= 1) {
        s += __shfl_xor(s, off);
        sq += __shfl_xor(sq, off);
    }
    float m = s * (1.0f / 128.0f);
    float var = sq * (1.0f / 128.0f) - m * m;
    float rs = rsqrtf(var + EPSV);
    o[(size_t)n * C_DIM + lane]      = f2b((v0 - m) * rs * g[lane] + b[lane]);
    o[(size_t)n * C_DIM + 64 + lane] = f2b((v1 - m) * rs * g[lane + 64] + b[lane + 64]);
}

// ---------------- bf16 MFMA GEMM, branch-paired via blockIdx.z ----------------
// EPI: 0 bf16 out; 1 f32 = acc+bias+res; 2 bf16 = gelu(acc+bias);
//      3 f32 split-K partial (z>>3 conv, z&7 K-slice);
//      4 gate: glo = acc+bias+res; out(C,N) = aux1 * sigmoid(aux0 + glo)
struct MArgs {
    const short* A[2]; const short* W[2];
    const float* bias[2]; const float* res[2];
    void* out[2];
    const float* aux0; const float* aux1;
};
template <int EPI>
__global__ __launch_bounds__(256) void mgemm_k(MArgs ga, int M, int N, int K, int kslice) {
    int zi    = (EPI == 3) ? (blockIdx.z >> 3) : blockIdx.z;
    int slice = (EPI == 3) ? (blockIdx.z & 7) : 0;
    const short* A = ga.A[zi];
    const short* W = ga.W[zi];
    __shared__ short As[128 * 64];
    __shared__ short Bs[128 * 64];
    int t = threadIdx.x;
    int w = t >> 6, l = t & 63;
    int m0 = blockIdx.x * 128, n0 = blockIdx.y * 128;
    int wm = (w >> 1) * 64, wn = (w & 1) * 64;
    int kbeg = (EPI == 3) ? slice * kslice : 0;
    int kend = kbeg + ((EPI == 3) ? kslice : K);

    f32x4 acc[4][4];
#pragma unroll
    for (int a = 0; a < 4; ++a)
#pragma unroll
        for (int b = 0; b < 4; ++b) acc[a][b] = f32x4{0.f, 0.f, 0.f, 0.f};

    for (int k0 = kbeg; k0 < kend; k0 += 64) {
        __syncthreads();
#pragma unroll
        for (int c = 0; c < 4; ++c) {
            int chunk = c * 256 + t;
            int row = chunk >> 3;
            int slot = chunk & 7;
            int ss = slot ^ (row & 7);
            uint4 av = *(const uint4*)(A + (size_t)(m0 + row) * K + k0 + slot * 8);
            *(uint4*)(As + row * 64 + ss * 8) = av;
            uint4 wv = *(const uint4*)(W + (size_t)(n0 + row) * K + k0 + slot * 8);
            *(uint4*)(Bs + row * 64 + ss * 8) = wv;
        }
        __syncthreads();
#pragma unroll
        for (int kk = 0; kk < 2; ++kk) {
            short8 af[4], bf[4];
            int sl = kk * 4 + (l >> 4);
#pragma unroll
            for (int mf = 0; mf < 4; ++mf) {
                int row = wm + mf * 16 + (l & 15);
                af[mf] = *(const short8*)(As + row * 64 + (sl ^ (row & 7)) * 8);
            }
#pragma unroll
            for (int nf = 0; nf < 4; ++nf) {
                int row = wn + nf * 16 + (l & 15);
                bf[nf] = *(const short8*)(Bs + row * 64 + (sl ^ (row & 7)) * 8);
            }
#pragma unroll
            for (int mf = 0; mf < 4; ++mf)
#pragma unroll
                for (int nf = 0; nf < 4; ++nf)
                    acc[mf][nf] = __builtin_amdgcn_mfma_f32_16x16x32_bf16(
                        af[mf], bf[nf], acc[mf][nf], 0, 0, 0);
        }
    }

#pragma unroll
    for (int mf = 0; mf < 4; ++mf) {
#pragma unroll
        for (int nf = 0; nf < 4; ++nf) {
            int col = n0 + wn + nf * 16 + (l & 15);
            int rowb = m0 + wm + mf * 16 + (l >> 4) * 4;
            if (EPI == 4) {
                f32x4 xv = *(const f32x4*)(ga.aux1 + (size_t)col * N_TOK + rowb);
                f32x4 ov;
#pragma unroll
                for (int j = 0; j < 4; ++j) {
                    int row = rowb + j;
                    float v = acc[mf][nf][j] + ga.bias[zi][col] + ga.res[zi][(size_t)row * N + col];
                    float z = ga.aux0[(size_t)row * N + col] + v;
                    float sg = 1.0f / (1.0f + __expf(-z));
                    ov[j] = xv[j] * sg;
                }
                *(f32x4*)((float*)ga.out[zi] + (size_t)col * N_TOK + rowb) = ov;
            } else {
#pragma unroll
                for (int j = 0; j < 4; ++j) {
                    int row = rowb + j;
                    float v = acc[mf][nf][j];
                    if (EPI == 0) {
                        ((short*)ga.out[zi])[(size_t)row * N + col] = f2b(v);
                    } else if (EPI == 1) {
                        v += ga.bias[zi][col] + ga.res[zi][(size_t)row * N + col];
                        ((float*)ga.out[zi])[(size_t)row * N + col] = v;
                    } else if (EPI == 2) {
                        v = gelu_f(v + ga.bias[zi][col]);
                        ((short*)ga.out[zi])[(size_t)row * N + col] = f2b(v);
                    } else if (EPI == 3) {
                        ((float*)ga.out[zi])[(size_t)slice * M * N + (size_t)row * N + col] = v;
                    }
                }
            }
        }
    }
}

// ------- fused: local patch attention (blocks 0..255) + K/V gather (blocks 256+) ----
__global__ __launch_bounds__(256) void lag_k(const short* __restrict__ qkv_l,
                                             const short* __restrict__ qkv_g,
                                             short* __restrict__ ob,
                                             short* __restrict__ kg, short* __restrict__ vg) {
    __shared__ float ks[NHD][32][HDIM];
    __shared__ float vs[NHD][32][HDIM];
    int t = threadIdx.x;
    if (blockIdx.x >= 256) {
        int idx = (blockIdx.x - 256) * 256 + t;
        int nr = idx >> 10, qq = idx & 1023;
        int ci = qq >> 3, off = qq & 7;
        int od = off >> 2, oh = (off >> 1) & 1, ow = off & 1;
        int d2 = nr >> 8, h2 = (nr >> 4) & 15, w2 = nr & 15;
        int n = (2 * d2 + od) * 1024 + (2 * h2 + oh) * 32 + (2 * w2 + ow);
        kg[idx] = qkv_g[(size_t)n * 384 + 128 + ci];
        vg[idx] = qkv_g[(size_t)n * 384 + 256 + ci];
        return;
    }
    int m = t & 31, h = t >> 5, r = blockIdx.x;
    int zd = r >> 6, zh = (r >> 3) & 7, zw = r & 7;
    int pd = m >> 4, ph = (m >> 2) & 3, pw = m & 3;
    int n = (zd * 2 + pd) * 1024 + (zh * 4 + ph) * 32 + (zw * 4 + pw);
    const short* base = qkv_l + (size_t)n * 384 + h * HDIM;
    float q[16], kt[16], vt[16];
    ld16bf(base, q);
    ld16bf(base + 128, kt);
    ld16bf(base + 256, vt);
#pragma unroll
    for (int d = 0; d < 16; ++d) { ks[h][m][d] = kt[d]; vs[h][m][d] = vt[d]; }
    __syncthreads();
    float s[32];
#pragma unroll
    for (int j = 0; j < 32; ++j) {
        float d = 0.f;
#pragma unroll
        for (int dd = 0; dd < 16; ++dd) d += q[dd] * ks[h][j][dd];
        s[j] = __expf(d * QK_SCALE);
    }
    float sum = 0.f;
#pragma unroll
    for (int j = 0; j < 32; ++j) sum += s[j];
    float inv = 1.0f / sum;
    float oo[16] = {};
#pragma unroll
    for (int j = 0; j < 32; ++j) {
        float p = s[j] * inv;
#pragma unroll
        for (int dd = 0; dd < 16; ++dd) oo[dd] += p * vs[h][j][dd];
    }
#pragma unroll
    for (int dd = 0; dd < 16; ++dd) {
        int n2 = h * 4 + (dd >> 2);
        int c2 = (dd & 3) * 32 + m;
        int pd2 = n2 >> 4, ph2 = (n2 >> 2) & 3, pw2 = n2 & 3;
        int nn = (zd * 2 + pd2) * 1024 + (zh * 4 + ph2) * 32 + (zw * 4 + pw2);
        ob[(size_t)nn * C_DIM + c2] = f2b(oo[dd]);
    }
}

// ------- sum 8 split-K partials + per-head LN; K -> bf16 *0.25*log2e, V -> bf16^T ---
__global__ __launch_bounds__(256) void ln_head_sum_k(const float* __restrict__ kpart,
                                                     const float* __restrict__ vpart,
                                                     const float* __restrict__ gk, const float* __restrict__ bk,
                                                     const float* __restrict__ gv, const float* __restrict__ bv,
                                                     short* __restrict__ kout, short* __restrict__ vout) {
    int idx = blockIdx.x * 256 + threadIdx.x;   // 0..16383
    bool sel = idx >= 8192;
    int id2 = idx & 8191;
    const float* part = sel ? vpart : kpart;
    const float* g    = sel ? gv : gk;
    const float* b    = sel ? bv : bk;
    int nr = id2 >> 3, h = id2 & 7;
    size_t base = (size_t)nr * C_DIM + h * HDIM;
    float v[16] = {};
#pragma unroll
    for (int p = 0; p < 8; ++p) {
        const float* pp = part + (size_t)p * (NR * C_DIM) + base;
#pragma unroll
        for (int d4 = 0; d4 < 4; ++d4) {
            float4 t = *(const float4*)(pp + d4 * 4);
            v[d4 * 4 + 0] += t.x; v[d4 * 4 + 1] += t.y;
            v[d4 * 4 + 2] += t.z; v[d4 * 4 + 3] += t.w;
        }
    }
    float s = 0.f;
#pragma unroll
    for (int i = 0; i < 16; ++i) s += v[i];
    float m = s * (1.0f / 16.0f);
    float sq = 0.f;
#pragma unroll
    for (int i = 0; i < 16; ++i) { float d = v[i] - m; sq += d * d; }
    float rs = rsqrtf(sq * (1.0f / 16.0f) + EPSV);
    if (!sel) {
        short* op = kout + (size_t)h * (NR * HDIM) + (size_t)nr * HDIM;
#pragma unroll
        for (int i = 0; i < 16; ++i)
            op[i] = f2b(((v[i] - m) * rs * g[i] + b[i]) * QK_L2E);
    } else {
        short* op = vout + (size_t)h * (HDIM * NR) + nr;
#pragma unroll
        for (int i = 0; i < 16; ++i)
            op[(size_t)i * NR] = f2b((v[i] - m) * rs * g[i] + b[i]);
    }
}

// ---------------- global attention v7: swapped QK^T, cvt_pk paired P stores --------
// grid (128, 8); block 256 = 4 waves; wave handles 16 q x 1024 keys.
// QK: mfma(K,Q) -> lane(lr,lq): q=lr, keys lq*4+j of each 16-key tile.
// P LDS [16 q][128 keys] bf16, XOR swizzle on key. PV unchanged (q=lr rows).
__global__ __launch_bounds__(256) void gattn_k(const short* __restrict__ qkv,
                                               const short* __restrict__ kb,   // [8][1024][16] *0.25*log2e
                                               const short* __restrict__ vt,   // [8][16][1024]
                                               short* __restrict__ ob) {
    __shared__ short plds[4][2048];
    int t = threadIdx.x;
    int w = t >> 6, l = t & 63;
    int h = blockIdx.y;
    int lr = l & 15, lq = l >> 4;
    int q0 = blockIdx.x * 64 + w * 16;

    short8 qf = short8{0, 0, 0, 0, 0, 0, 0, 0};
    if (lq < 2)
        qf = *(const short8*)(qkv + (size_t)(q0 + lr) * 384 + h * HDIM + lq * 8);

    const short* kh = kb + (size_t)h * (NR * HDIM);
    const short* vh = vt + (size_t)h * (HDIM * NR);
    short* pw = &plds[w][0];

    const f32x4 zz = {0.f, 0.f, 0.f, 0.f};
    f32x4 oacc = {0.f, 0.f, 0.f, 0.f};
    float rs = 0.f;

    for (int c = 0; c < 8; ++c) {
        int kbase = c * 128;
        f32x4 s[8];
#pragma unroll
        for (int nf = 0; nf < 8; ++nf) {
            short8 kf = short8{0, 0, 0, 0, 0, 0, 0, 0};
            if (lq < 2)
                kf = *(const short8*)(kh + (size_t)(kbase + nf * 16 + lr) * HDIM + lq * 8);
            s[nf] = __builtin_amdgcn_mfma_f32_16x16x32_bf16(kf, qf, zz, 0, 0, 0);
        }
#pragma unroll
        for (int nf = 0; nf < 8; ++nf) {
            float p0 = exp2f(s[nf][0]);
            float p1 = exp2f(s[nf][1]);
            float p2 = exp2f(s[nf][2]);
            float p3 = exp2f(s[nf][3]);
            rs += (p0 + p1) + (p2 + p3);
            unsigned int u01, u23;
            asm("v_cvt_pk_bf16_f32 %0, %1, %2" : "=v"(u01) : "v"(p0), "v"(p1));
            asm("v_cvt_pk_bf16_f32 %0, %1, %2" : "=v"(u23) : "v"(p2), "v"(p3));
            int k0 = nf * 16 + lq * 4;   // lane's 4 consecutive keys (q = lr)
            int sw = (lr & 7) << 3;
            *(unsigned int*)&pw[lr * 128 + (k0 ^ sw)]       = u01;
            *(unsigned int*)&pw[lr * 128 + ((k0 + 2) ^ sw)] = u23;
        }
#pragma unroll
        for (int ks = 0; ks < 4; ++ks) {
            short8 pf = *(const short8*)&pw[(lr * 128 + ks * 32 + lq * 8) ^ ((lr & 7) << 3)];
            short8 vf = *(const short8*)(vh + (size_t)lr * NR + kbase + ks * 32 + lq * 8);
            oacc = __builtin_amdgcn_mfma_f32_16x16x32_bf16(pf, vf, oacc, 0, 0, 0);
        }
    }
    // lane holds partial row-sum for q=lr over its key subset -> combine lq copies
    rs += __shfl_xor(rs, 16);
    rs += __shfl_xor(rs, 32);
    // PV output: lane(lr,lq) holds q_out = lq*4+j, d = lr; fetch matching row sums
    float r0 = __shfl(rs, lq * 4 + 0);
    float r1 = __shfl(rs, lq * 4 + 1);
    float r2 = __shfl(rs, lq * 4 + 2);
    float r3 = __shfl(rs, lq * 4 + 3);
    size_t base_o = (size_t)(q0 + lq * 4) * C_DIM + h * HDIM + lr;
    ob[base_o]             = f2b(oacc[0] / r0);
    ob[base_o + C_DIM]     = f2b(oacc[1] / r1);
    ob[base_o + 2 * C_DIM] = f2b(oacc[2] / r2);
    ob[base_o + 3 * C_DIM] = f2b(oacc[3] / r3);
}

extern "C" void kernel_launch(void* const* d_in, const int* in_sizes, int n_in,
                              void* d_out, int out_size, void* d_ws, size_t ws_size,
                              hipStream_t stream) {
    const float* x        = (const float*)d_in[0];
    const float* l_n1_g   = (const float*)d_in[1];
    const float* l_n1_b   = (const float*)d_in[2];
    const float* l_qkv_w  = (const float*)d_in[3];
    const float* l_proj_w = (const float*)d_in[4];
    const float* l_proj_b = (const float*)d_in[5];
    const float* l_n2_g   = (const float*)d_in[6];
    const float* l_n2_b   = (const float*)d_in[7];
    const float* l_fc1_w  = (const float*)d_in[8];
    const float* l_fc1_b  = (const float*)d_in[9];
    const float* l_fc2_w  = (const float*)d_in[10];
    const float* l_fc2_b  = (const float*)d_in[11];
    const float* g_n1_g   = (const float*)d_in[12];
    const float* g_n1_b   = (const float*)d_in[13];
    const float* g_qkv_w  = (const float*)d_in[14];
    const float* g_proj_w = (const float*)d_in[15];
    const float* g_proj_b = (const float*)d_in[16];
    const float* g_n2_g   = (const float*)d_in[17];
    const float* g_n2_b   = (const float*)d_in[18];
    const float* g_fc1_w  = (const float*)d_in[19];
    const float* g_fc1_b  = (const float*)d_in[20];
    const float* g_fc2_w  = (const float*)d_in[21];
    const float* g_fc2_b  = (const float*)d_in[22];
    const float* g_ke_w   = (const float*)d_in[23];
    const float* g_ve_w   = (const float*)d_in[24];
    const float* g_nk_g   = (const float*)d_in[25];
    const float* g_nk_b   = (const float*)d_in[26];
    const float* g_nv_g   = (const float*)d_in[27];
    const float* g_nv_b   = (const float*)d_in[28];
    float* out = (float*)d_out;

    char* base = (char*)d_ws;
    float* xt     = (float*)(base);                        // 0-4 MB
    float* t1_l   = (float*)(base + (4ull  << 20));        // 4-8 MB
    float* t1_g   = (float*)(base + (8ull  << 20));        // 8-12 MB
    short* yA16   = (short*)(base + (12ull << 20));        // 12-14 (later t2_l)
    short* yG16   = (short*)(base + (14ull << 20));        // 14-16 (later t2_g)
    short* t2_l   = yA16;
    short* t2_g   = yG16;
    float* locfin = (float*)(base + (12ull << 20));        // 12-16 (after fc1 reads t2)
    short* obuf_l = (short*)(base + (16ull << 20));        // 16-18
    short* obuf_g = (short*)(base + (18ull << 20));        // 18-20
    short* qkv_l  = (short*)(base + (20ull << 20));        // 20-26
    short* qkv_g  = (short*)(base + (26ull << 20));        // 26-32
    short* h1_l   = (short*)(base + (32ull << 20));        // 32-40 (after ln_head)
    float* kpart  = (float*)(base + (32ull << 20));        // 32-36 (pre-fc1)
    float* vpart  = (float*)(base + (36ull << 20));        // 36-40 (pre-fc1)
    short* h1_g   = (short*)(base + (40ull << 20));        // 40-48 (after conv)
    short* kg16   = (short*)(base + (40ull << 20));        // 40-42 (pre-fc1)
    short* vg16   = (short*)(base + (42ull << 20));        // 42-44 (pre-fc1)
    short* kb16   = (short*)(base + (48ull << 20));        // [8][1024][16]
    short* vt16   = (short*)(base + (48ull << 20) + (512ull << 10)); // [8][16][1024]
    short* wts    = (short*)(base + (49ull << 20));        // ~1.3 MB

    const int L_QKV = 0,      L_PROJ = 49152, L_FC1 = 65536,  L_FC2 = 131072;
    const int G_QKV = 196608, G_PROJ = 245760, G_FC1 = 262144, G_FC2 = 327680;
    const int G_KE  = 393216, G_VE   = 524288;

    CvtArgs ca;
    ca.d[0] = {l_qkv_w,  wts + L_QKV,  49152, 0};
    ca.d[1] = {l_proj_w, wts + L_PROJ, 16384, 0};
    ca.d[2] = {l_fc1_w,  wts + L_FC1,  65536, 0};
    ca.d[3] = {l_fc2_w,  wts + L_FC2,  65536, 0};
    ca.d[4] = {g_qkv_w,  wts + G_QKV,  49152, 0};
    ca.d[5] = {g_proj_w, wts + G_PROJ, 16384, 0};
    ca.d[6] = {g_fc1_w,  wts + G_FC1,  65536, 0};
    ca.d[7] = {g_fc2_w,  wts + G_FC2,  65536, 0};
    ca.d[8] = {g_ke_w,   wts + G_KE,  131072, 0};
    ca.d[9] = {g_ve_w,   wts + G_VE,  131072, 0};

    // 1: transpose + LN1 + weight cvt
    xlncvt_k<<<168, 256, 0, stream>>>(x, l_n1_g, l_n1_b, g_n1_g, g_n1_b, xt, yA16, yG16, ca);

    // 2: both qkv GEMMs
    MArgs a_qkv = {{yA16, yG16}, {wts + L_QKV, wts + G_QKV}, {nullptr, nullptr}, {nullptr, nullptr}, {qkv_l, qkv_g}, nullptr, nullptr};
    mgemm_k<0><<<dim3(64, 3, 2), 256, 0, stream>>>(a_qkv, N_TOK, 384, 128, 0);

    // 3: local attention + global gather (fused)
    lag_k<<<4352, 256, 0, stream>>>(qkv_l, qkv_g, obuf_l, kg16, vg16);

    // 4: both conv reductions, split-K x8
    MArgs a_cv = {{kg16, vg16}, {wts + G_KE, wts + G_VE}, {nullptr, nullptr}, {nullptr, nullptr}, {kpart, vpart}, nullptr, nullptr};
    mgemm_k<3><<<dim3(8, 1, 16), 256, 0, stream>>>(a_cv, NR, 128, 1024, 128);

    // 5: head-LN for K (scaled for exp2) and V^T
    ln_head_sum_k<<<64, 256, 0, stream>>>(kpart, vpart, g_nk_g, g_nk_b, g_nv_g, g_nv_b, kb16, vt16);

    // 6: global attention (MFMA flash v7)
    gattn_k<<<dim3(128, 8), 256, 0, stream>>>(qkv_g, kb16, vt16, obuf_g);

    // 7: both proj GEMMs (+bias+residual)
    MArgs a_pj = {{obuf_l, obuf_g}, {wts + L_PROJ, wts + G_PROJ}, {l_proj_b, g_proj_b}, {xt, xt}, {t1_l, t1_g}, nullptr, nullptr};
    mgemm_k<1><<<dim3(64, 1, 2), 256, 0, stream>>>(a_pj, N_TOK, 128, 128, 0);

    // 8: both second LNs
    ln2_pair_k<<<4096, 256, 0, stream>>>(t1_l, l_n2_g, l_n2_b, t2_l, t1_g, g_n2_g, g_n2_b, t2_g);

    // 9: both fc1 GEMMs (+bias+gelu)
    MArgs a_f1 = {{t2_l, t2_g}, {wts + L_FC1, wts + G_FC1}, {l_fc1_b, g_fc1_b}, {nullptr, nullptr}, {h1_l, h1_g}, nullptr, nullptr};
    mgemm_k<2><<<dim3(64, 4, 2), 256, 0, stream>>>(a_f1, N_TOK, 512, 128, 0);

    // 10: local fc2 (+bias+residual) -> locfin f32
    MArgs a_f2l = {{h1_l, nullptr}, {wts + L_FC2, nullptr}, {l_fc2_b, nullptr}, {t1_l, nullptr}, {locfin, nullptr}, nullptr, nullptr};
    mgemm_k<1><<<dim3(64, 1, 1), 256, 0, stream>>>(a_f2l, N_TOK, 128, 512, 0);

    // 11: global fc2 + gate fused -> out (C,N)
    MArgs a_f2g = {{h1_g, nullptr}, {wts + G_FC2, nullptr}, {g_fc2_b, nullptr}, {t1_g, nullptr}, {out, nullptr}, locfin, x};
    mgemm_k<4><<<dim3(64, 1, 1), 256, 0, stream>>>(a_f2g, N_TOK, 128, 512, 0);
}

// Round 8
// 143.989 us; speedup vs baseline: 1.0894x; 1.0894x over previous
//
#include <hip/hip_runtime.h>
#include <math.h>

#define N_TOK 8192
#define C_DIM 128
#define NHD   8
#define HDIM  16
#define NR    1024
#define EPSV  1e-5f
#define QK_SCALE 0.25f
#define QK_L2E  0.36067376f   /* 0.25 * log2(e) */

typedef __attribute__((ext_vector_type(8))) short short8;
typedef __attribute__((ext_vector_type(4))) float f32x4;

__device__ __forceinline__ float gelu_f(float v) {
    return 0.5f * v * (1.0f + erff(v * 0.70710678118654752f));
}
__device__ __forceinline__ float uaf(unsigned int u) {
    union { unsigned int u; float f; } x; x.u = u; return x.f;
}
__device__ __forceinline__ short f2b(float v) {
    union { float f; unsigned int u; } x; x.f = v;
    unsigned int r = x.u + 0x7fffu + ((x.u >> 16) & 1u);
    return (short)(r >> 16);
}
__device__ __forceinline__ void ld16bf(const short* p, float* d) {
    uint4 a = *(const uint4*)p;
    uint4 b = *(const uint4*)(p + 8);
    d[0]  = uaf(a.x << 16); d[1]  = uaf(a.x & 0xffff0000u);
    d[2]  = uaf(a.y << 16); d[3]  = uaf(a.y & 0xffff0000u);
    d[4]  = uaf(a.z << 16); d[5]  = uaf(a.z & 0xffff0000u);
    d[6]  = uaf(a.w << 16); d[7]  = uaf(a.w & 0xffff0000u);
    d[8]  = uaf(b.x << 16); d[9]  = uaf(b.x & 0xffff0000u);
    d[10] = uaf(b.y << 16); d[11] = uaf(b.y & 0xffff0000u);
    d[12] = uaf(b.z << 16); d[13] = uaf(b.z & 0xffff0000u);
    d[14] = uaf(b.w << 16); d[15] = uaf(b.w & 0xffff0000u);
}

// ---------------- weight fp32 -> bf16 conversion ----------------
struct CvtDesc { const float* src; short* dst; int n; int pad; };
struct CvtArgs { CvtDesc d[10]; };
__global__ __launch_bounds__(256) void cvtw_k(CvtArgs a) {
    CvtDesc dd = a.d[blockIdx.y];
    for (int i = blockIdx.x * 256 + threadIdx.x; i < dd.n; i += gridDim.x * 256)
        dd.dst[i] = f2b(dd.src[i]);
}

// ---------------- transpose x (C,N) -> xt (N,C) f32 ----------------
__global__ __launch_bounds__(256) void transpose_k(const float* __restrict__ x,
                                                   float* __restrict__ xt) {
    __shared__ float tile[32][33];
    int n0 = blockIdx.x * 32, c0 = blockIdx.y * 32;
    int tx = threadIdx.x, ty = threadIdx.y;
#pragma unroll
    for (int k = 0; k < 4; ++k)
        tile[ty + k * 8][tx] = x[(size_t)(c0 + ty + k * 8) * N_TOK + n0 + tx];
    __syncthreads();
#pragma unroll
    for (int k = 0; k < 4; ++k)
        xt[(size_t)(n0 + ty + k * 8) * C_DIM + c0 + tx] = tile[tx][ty + k * 8];
}

// ---------------- first LN: fp32 in, two bf16 outputs ----------------
__global__ __launch_bounds__(256) void ln_token_k(const float* __restrict__ in,
                                                  const float* __restrict__ g1, const float* __restrict__ b1,
                                                  short* __restrict__ o1,
                                                  const float* __restrict__ g2, const float* __restrict__ b2,
                                                  short* __restrict__ o2) {
    int lane = threadIdx.x & 63;
    int n = blockIdx.x * 4 + (threadIdx.x >> 6);
    float v0 = in[(size_t)n * C_DIM + lane];
    float v1 = in[(size_t)n * C_DIM + 64 + lane];
    float s = v0 + v1, sq = v0 * v0 + v1 * v1;
#pragma unroll
    for (int off = 32; off >= 1; off >>= 1) {
        s += __shfl_xor(s, off);
        sq += __shfl_xor(sq, off);
    }
    float m = s * (1.0f / 128.0f);
    float var = sq * (1.0f / 128.0f) - m * m;
    float rs = rsqrtf(var + EPSV);
    float h0 = (v0 - m) * rs, h1 = (v1 - m) * rs;
    o1[(size_t)n * C_DIM + lane]      = f2b(h0 * g1[lane] + b1[lane]);
    o1[(size_t)n * C_DIM + 64 + lane] = f2b(h1 * g1[lane + 64] + b1[lane + 64]);
    o2[(size_t)n * C_DIM + lane]      = f2b(h0 * g2[lane] + b2[lane]);
    o2[(size_t)n * C_DIM + 64 + lane] = f2b(h1 * g2[lane + 64] + b2[lane + 64]);
}

// ---------------- second LN, paired across branches ----------------
__global__ __launch_bounds__(256) void ln2_pair_k(const float* __restrict__ in0,
                                                  const float* __restrict__ g0, const float* __restrict__ b0,
                                                  short* __restrict__ o0,
                                                  const float* __restrict__ in1,
                                                  const float* __restrict__ g1, const float* __restrict__ b1,
                                                  short* __restrict__ o1) {
    int blk = blockIdx.x;
    bool sel = blk >= 2048;
    blk &= 2047;
    const float* in = sel ? in1 : in0;
    const float* g  = sel ? g1 : g0;
    const float* b  = sel ? b1 : b0;
    short* o        = sel ? o1 : o0;
    int lane = threadIdx.x & 63;
    int n = blk * 4 + (threadIdx.x >> 6);
    float v0 = in[(size_t)n * C_DIM + lane];
    float v1 = in[(size_t)n * C_DIM + 64 + lane];
    float s = v0 + v1, sq = v0 * v0 + v1 * v1;
#pragma unroll
    for (int off = 32; off >= 1; off >>= 1) {
        s += __shfl_xor(s, off);
        sq += __shfl_xor(sq, off);
    }
    float m = s * (1.0f / 128.0f);
    float var = sq * (1.0f / 128.0f) - m * m;
    float rs = rsqrtf(var + EPSV);
    o[(size_t)n * C_DIM + lane]      = f2b((v0 - m) * rs * g[lane] + b[lane]);
    o[(size_t)n * C_DIM + 64 + lane] = f2b((v1 - m) * rs * g[lane + 64] + b[lane + 64]);
}

// ---------------- bf16 MFMA GEMM, branch-paired via blockIdx.z ----------------
// EPI: 0 bf16 out; 1 f32 = acc+bias+res; 2 bf16 = gelu(acc+bias);
//      3 f32 split-K partial (z>>3 conv, z&7 K-slice)
struct MArgs {
    const short* A[2]; const short* W[2];
    const float* bias[2]; const float* res[2];
    void* out[2];
};
template <int EPI>
__global__ __launch_bounds__(256) void mgemm_k(MArgs ga, int M, int N, int K, int kslice) {
    int zi    = (EPI == 3) ? (blockIdx.z >> 3) : blockIdx.z;
    int slice = (EPI == 3) ? (blockIdx.z & 7) : 0;
    const short* A = ga.A[zi];
    const short* W = ga.W[zi];
    __shared__ short As[128 * 64];
    __shared__ short Bs[128 * 64];
    int t = threadIdx.x;
    int w = t >> 6, l = t & 63;
    int m0 = blockIdx.x * 128, n0 = blockIdx.y * 128;
    int wm = (w >> 1) * 64, wn = (w & 1) * 64;
    int kbeg = (EPI == 3) ? slice * kslice : 0;
    int kend = kbeg + ((EPI == 3) ? kslice : K);

    f32x4 acc[4][4];
#pragma unroll
    for (int a = 0; a < 4; ++a)
#pragma unroll
        for (int b = 0; b < 4; ++b) acc[a][b] = f32x4{0.f, 0.f, 0.f, 0.f};

    for (int k0 = kbeg; k0 < kend; k0 += 64) {
        __syncthreads();
#pragma unroll
        for (int c = 0; c < 4; ++c) {
            int chunk = c * 256 + t;
            int row = chunk >> 3;
            int slot = chunk & 7;
            int ss = slot ^ (row & 7);
            uint4 av = *(const uint4*)(A + (size_t)(m0 + row) * K + k0 + slot * 8);
            *(uint4*)(As + row * 64 + ss * 8) = av;
            uint4 wv = *(const uint4*)(W + (size_t)(n0 + row) * K + k0 + slot * 8);
            *(uint4*)(Bs + row * 64 + ss * 8) = wv;
        }
        __syncthreads();
#pragma unroll
        for (int kk = 0; kk < 2; ++kk) {
            short8 af[4], bf[4];
            int sl = kk * 4 + (l >> 4);
#pragma unroll
            for (int mf = 0; mf < 4; ++mf) {
                int row = wm + mf * 16 + (l & 15);
                af[mf] = *(const short8*)(As + row * 64 + (sl ^ (row & 7)) * 8);
            }
#pragma unroll
            for (int nf = 0; nf < 4; ++nf) {
                int row = wn + nf * 16 + (l & 15);
                bf[nf] = *(const short8*)(Bs + row * 64 + (sl ^ (row & 7)) * 8);
            }
#pragma unroll
            for (int mf = 0; mf < 4; ++mf)
#pragma unroll
                for (int nf = 0; nf < 4; ++nf)
                    acc[mf][nf] = __builtin_amdgcn_mfma_f32_16x16x32_bf16(
                        af[mf], bf[nf], acc[mf][nf], 0, 0, 0);
        }
    }

    // C/D layout: col = lane&15, row = (lane>>4)*4 + reg
#pragma unroll
    for (int mf = 0; mf < 4; ++mf) {
#pragma unroll
        for (int nf = 0; nf < 4; ++nf) {
            int col = n0 + wn + nf * 16 + (l & 15);
#pragma unroll
            for (int j = 0; j < 4; ++j) {
                int row = m0 + wm + mf * 16 + (l >> 4) * 4 + j;
                float v = acc[mf][nf][j];
                if (EPI == 0) {
                    ((short*)ga.out[zi])[(size_t)row * N + col] = f2b(v);
                } else if (EPI == 1) {
                    v += ga.bias[zi][col] + ga.res[zi][(size_t)row * N + col];
                    ((float*)ga.out[zi])[(size_t)row * N + col] = v;
                } else if (EPI == 2) {
                    v = gelu_f(v + ga.bias[zi][col]);
                    ((short*)ga.out[zi])[(size_t)row * N + col] = f2b(v);
                } else {
                    ((float*)ga.out[zi])[(size_t)slice * M * N + (size_t)row * N + col] = v;
                }
            }
        }
    }
}

// ---------------- local patch attention, bf16 in/out ----------------
__global__ __launch_bounds__(256) void local_attn_k(const short* __restrict__ qkv,
                                                    short* __restrict__ ob) {
    __shared__ float ks[NHD][32][HDIM];
    __shared__ float vs[NHD][32][HDIM];
    int m = threadIdx.x, h = threadIdx.y, r = blockIdx.x;
    int zd = r >> 6, zh = (r >> 3) & 7, zw = r & 7;
    int pd = m >> 4, ph = (m >> 2) & 3, pw = m & 3;
    int n = (zd * 2 + pd) * 1024 + (zh * 4 + ph) * 32 + (zw * 4 + pw);
    const short* base = qkv + (size_t)n * 384 + h * HDIM;
    float q[16], kt[16], vt[16];
    ld16bf(base, q);
    ld16bf(base + 128, kt);
    ld16bf(base + 256, vt);
#pragma unroll
    for (int d = 0; d < 16; ++d) { ks[h][m][d] = kt[d]; vs[h][m][d] = vt[d]; }
    __syncthreads();
    float s[32];
#pragma unroll
    for (int j = 0; j < 32; ++j) {
        float d = 0.f;
#pragma unroll
        for (int dd = 0; dd < 16; ++dd) d += q[dd] * ks[h][j][dd];
        s[j] = __expf(d * QK_SCALE);
    }
    float sum = 0.f;
#pragma unroll
    for (int j = 0; j < 32; ++j) sum += s[j];
    float inv = 1.0f / sum;
    float oo[16] = {};
#pragma unroll
    for (int j = 0; j < 32; ++j) {
        float p = s[j] * inv;
#pragma unroll
        for (int dd = 0; dd < 16; ++dd) oo[dd] += p * vs[h][j][dd];
    }
    // torch-faithful quirk: o (NH,Npl,HD) -> swap(-1,-2) -> reshape (Npl, C)
#pragma unroll
    for (int dd = 0; dd < 16; ++dd) {
        int n2 = h * 4 + (dd >> 2);
        int c2 = (dd & 3) * 32 + m;
        int pd2 = n2 >> 4, ph2 = (n2 >> 2) & 3, pw2 = n2 & 3;
        int nn = (zd * 2 + pd2) * 1024 + (zh * 4 + ph2) * 32 + (zw * 4 + pw2);
        ob[(size_t)nn * C_DIM + c2] = f2b(oo[dd]);
    }
}

// ---------------- gather reduced K/V conv inputs ----------------
__global__ __launch_bounds__(256) void gather_k(const short* __restrict__ qkv,
                                                short* __restrict__ kg, short* __restrict__ vg) {
    int idx = blockIdx.x * 256 + threadIdx.x;
    int nr = idx >> 10, qq = idx & 1023;
    int ci = qq >> 3, off = qq & 7;
    int od = off >> 2, oh = (off >> 1) & 1, ow = off & 1;
    int d2 = nr >> 8, h2 = (nr >> 4) & 15, w2 = nr & 15;
    int n = (2 * d2 + od) * 1024 + (2 * h2 + oh) * 32 + (2 * w2 + ow);
    kg[idx] = qkv[(size_t)n * 384 + 128 + ci];
    vg[idx] = qkv[(size_t)n * 384 + 256 + ci];
}

// ------- sum 8 split-K partials + per-head LN; K -> bf16 *0.25*log2e, V -> bf16^T ---
__global__ __launch_bounds__(256) void ln_head_sum_k(const float* __restrict__ kpart,
                                                     const float* __restrict__ vpart,
                                                     const float* __restrict__ gk, const float* __restrict__ bk,
                                                     const float* __restrict__ gv, const float* __restrict__ bv,
                                                     short* __restrict__ kout, short* __restrict__ vout) {
    int idx = blockIdx.x * 256 + threadIdx.x;   // 0..16383
    bool sel = idx >= 8192;
    int id2 = idx & 8191;
    const float* part = sel ? vpart : kpart;
    const float* g    = sel ? gv : gk;
    const float* b    = sel ? bv : bk;
    int nr = id2 >> 3, h = id2 & 7;
    size_t base = (size_t)nr * C_DIM + h * HDIM;
    float v[16] = {};
#pragma unroll
    for (int p = 0; p < 8; ++p) {
        const float* pp = part + (size_t)p * (NR * C_DIM) + base;
#pragma unroll
        for (int d4 = 0; d4 < 4; ++d4) {
            float4 t = *(const float4*)(pp + d4 * 4);
            v[d4 * 4 + 0] += t.x; v[d4 * 4 + 1] += t.y;
            v[d4 * 4 + 2] += t.z; v[d4 * 4 + 3] += t.w;
        }
    }
    float s = 0.f;
#pragma unroll
    for (int i = 0; i < 16; ++i) s += v[i];
    float m = s * (1.0f / 16.0f);
    float sq = 0.f;
#pragma unroll
    for (int i = 0; i < 16; ++i) { float d = v[i] - m; sq += d * d; }
    float rs = rsqrtf(sq * (1.0f / 16.0f) + EPSV);
    if (!sel) {
        short* op = kout + (size_t)h * (NR * HDIM) + (size_t)nr * HDIM;
#pragma unroll
        for (int i = 0; i < 16; ++i)
            op[i] = f2b(((v[i] - m) * rs * g[i] + b[i]) * QK_L2E);
    } else {
        short* op = vout + (size_t)h * (HDIM * NR) + nr;
#pragma unroll
        for (int i = 0; i < 16; ++i)
            op[(size_t)i * NR] = f2b((v[i] - m) * rs * g[i] + b[i]);
    }
}

// ---------------- global attention v7: swapped QK^T, cvt_pk paired P stores --------
__global__ __launch_bounds__(256) void gattn_k(const short* __restrict__ qkv,
                                               const short* __restrict__ kb,   // [8][1024][16] *0.25*log2e
                                               const short* __restrict__ vt,   // [8][16][1024]
                                               short* __restrict__ ob) {
    __shared__ short plds[4][2048];
    int t = threadIdx.x;
    int w = t >> 6, l = t & 63;
    int h = blockIdx.y;
    int lr = l & 15, lq = l >> 4;
    int q0 = blockIdx.x * 64 + w * 16;

    short8 qf = short8{0, 0, 0, 0, 0, 0, 0, 0};
    if (lq < 2)
        qf = *(const short8*)(qkv + (size_t)(q0 + lr) * 384 + h * HDIM + lq * 8);

    const short* kh = kb + (size_t)h * (NR * HDIM);
    const short* vh = vt + (size_t)h * (HDIM * NR);
    short* pw = &plds[w][0];

    const f32x4 zz = {0.f, 0.f, 0.f, 0.f};
    f32x4 oacc = {0.f, 0.f, 0.f, 0.f};
    float rs = 0.f;

    for (int c = 0; c < 8; ++c) {
        int kbase = c * 128;
        f32x4 s[8];
#pragma unroll
        for (int nf = 0; nf < 8; ++nf) {
            short8 kf = short8{0, 0, 0, 0, 0, 0, 0, 0};
            if (lq < 2)
                kf = *(const short8*)(kh + (size_t)(kbase + nf * 16 + lr) * HDIM + lq * 8);
            s[nf] = __builtin_amdgcn_mfma_f32_16x16x32_bf16(kf, qf, zz, 0, 0, 0);
        }
#pragma unroll
        for (int nf = 0; nf < 8; ++nf) {
            float p0 = exp2f(s[nf][0]);
            float p1 = exp2f(s[nf][1]);
            float p2 = exp2f(s[nf][2]);
            float p3 = exp2f(s[nf][3]);
            rs += (p0 + p1) + (p2 + p3);
            unsigned int u01, u23;
            asm("v_cvt_pk_bf16_f32 %0, %1, %2" : "=v"(u01) : "v"(p0), "v"(p1));
            asm("v_cvt_pk_bf16_f32 %0, %1, %2" : "=v"(u23) : "v"(p2), "v"(p3));
            int k0 = nf * 16 + lq * 4;
            int sw = (lr & 7) << 3;
            *(unsigned int*)&pw[lr * 128 + (k0 ^ sw)]       = u01;
            *(unsigned int*)&pw[lr * 128 + ((k0 + 2) ^ sw)] = u23;
        }
#pragma unroll
        for (int ks = 0; ks < 4; ++ks) {
            short8 pf = *(const short8*)&pw[(lr * 128 + ks * 32 + lq * 8) ^ ((lr & 7) << 3)];
            short8 vf = *(const short8*)(vh + (size_t)lr * NR + kbase + ks * 32 + lq * 8);
            oacc = __builtin_amdgcn_mfma_f32_16x16x32_bf16(pf, vf, oacc, 0, 0, 0);
        }
    }
    rs += __shfl_xor(rs, 16);
    rs += __shfl_xor(rs, 32);
    float r0 = __shfl(rs, lq * 4 + 0);
    float r1 = __shfl(rs, lq * 4 + 1);
    float r2 = __shfl(rs, lq * 4 + 2);
    float r3 = __shfl(rs, lq * 4 + 3);
    size_t base_o = (size_t)(q0 + lq * 4) * C_DIM + h * HDIM + lr;
    ob[base_o]             = f2b(oacc[0] / r0);
    ob[base_o + C_DIM]     = f2b(oacc[1] / r1);
    ob[base_o + 2 * C_DIM] = f2b(oacc[2] / r2);
    ob[base_o + 3 * C_DIM] = f2b(oacc[3] / r3);
}

// ---------------- final gate: out(C,N) = x * sigmoid(loc + glo) ----------------
__global__ __launch_bounds__(256) void gate_k(const float* __restrict__ x,
                                              const float* __restrict__ lf, const float* __restrict__ gf,
                                              float* __restrict__ out) {
    __shared__ float tile[32][33];
    int n0 = blockIdx.x * 32, c0 = blockIdx.y * 32;
    int tx = threadIdx.x, ty = threadIdx.y;
#pragma unroll
    for (int k = 0; k < 4; ++k) {
        int n = n0 + ty + k * 8, c = c0 + tx;
        tile[ty + k * 8][tx] = lf[(size_t)n * C_DIM + c] + gf[(size_t)n * C_DIM + c];
    }
    __syncthreads();
#pragma unroll
    for (int k = 0; k < 4; ++k) {
        int c = c0 + ty + k * 8, n = n0 + tx;
        float z = tile[tx][ty + k * 8];
        float sg = 1.0f / (1.0f + __expf(-z));
        out[(size_t)c * N_TOK + n] = x[(size_t)c * N_TOK + n] * sg;
    }
}

extern "C" void kernel_launch(void* const* d_in, const int* in_sizes, int n_in,
                              void* d_out, int out_size, void* d_ws, size_t ws_size,
                              hipStream_t stream) {
    const float* x        = (const float*)d_in[0];
    const float* l_n1_g   = (const float*)d_in[1];
    const float* l_n1_b   = (const float*)d_in[2];
    const float* l_qkv_w  = (const float*)d_in[3];
    const float* l_proj_w = (const float*)d_in[4];
    const float* l_proj_b = (const float*)d_in[5];
    const float* l_n2_g   = (const float*)d_in[6];
    const float* l_n2_b   = (const float*)d_in[7];
    const float* l_fc1_w  = (const float*)d_in[8];
    const float* l_fc1_b  = (const float*)d_in[9];
    const float* l_fc2_w  = (const float*)d_in[10];
    const float* l_fc2_b  = (const float*)d_in[11];
    const float* g_n1_g   = (const float*)d_in[12];
    const float* g_n1_b   = (const float*)d_in[13];
    const float* g_qkv_w  = (const float*)d_in[14];
    const float* g_proj_w = (const float*)d_in[15];
    const float* g_proj_b = (const float*)d_in[16];
    const float* g_n2_g   = (const float*)d_in[17];
    const float* g_n2_b   = (const float*)d_in[18];
    const float* g_fc1_w  = (const float*)d_in[19];
    const float* g_fc1_b  = (const float*)d_in[20];
    const float* g_fc2_w  = (const float*)d_in[21];
    const float* g_fc2_b  = (const float*)d_in[22];
    const float* g_ke_w   = (const float*)d_in[23];
    const float* g_ve_w   = (const float*)d_in[24];
    const float* g_nk_g   = (const float*)d_in[25];
    const float* g_nk_b   = (const float*)d_in[26];
    const float* g_nv_g   = (const float*)d_in[27];
    const float* g_nv_b   = (const float*)d_in[28];
    float* out = (float*)d_out;

    char* base = (char*)d_ws;
    float* xt     = (float*)(base);                        // 0-4 MB
    float* t1_l   = (float*)(base + (4ull  << 20));        // 4-8 MB
    float* t1_g   = (float*)(base + (8ull  << 20));        // 8-12 MB
    short* yA16   = (short*)(base + (12ull << 20));        // 12-14 (later t2_l)
    short* yG16   = (short*)(base + (14ull << 20));        // 14-16 (later t2_g)
    short* t2_l   = yA16;
    short* t2_g   = yG16;
    float* locfin = (float*)(base + (12ull << 20));        // 12-16 (after fc1 reads t2)
    short* obuf_l = (short*)(base + (16ull << 20));        // 16-18
    short* obuf_g = (short*)(base + (18ull << 20));        // 18-20
    float* glofin = (float*)(base + (16ull << 20));        // 16-20 (after proj reads obuf)
    short* qkv_l  = (short*)(base + (20ull << 20));        // 20-26
    short* qkv_g  = (short*)(base + (26ull << 20));        // 26-32
    short* h1_l   = (short*)(base + (32ull << 20));        // 32-40 (after ln_head)
    float* kpart  = (float*)(base + (32ull << 20));        // 32-36 (pre-fc1)
    float* vpart  = (float*)(base + (36ull << 20));        // 36-40 (pre-fc1)
    short* h1_g   = (short*)(base + (40ull << 20));        // 40-48 (after conv)
    short* kg16   = (short*)(base + (40ull << 20));        // 40-42 (pre-fc1)
    short* vg16   = (short*)(base + (42ull << 20));        // 42-44 (pre-fc1)
    short* kb16   = (short*)(base + (48ull << 20));        // [8][1024][16]
    short* vt16   = (short*)(base + (48ull << 20) + (512ull << 10)); // [8][16][1024]
    short* wts    = (short*)(base + (49ull << 20));        // ~1.3 MB

    const int L_QKV = 0,      L_PROJ = 49152, L_FC1 = 65536,  L_FC2 = 131072;
    const int G_QKV = 196608, G_PROJ = 245760, G_FC1 = 262144, G_FC2 = 327680;
    const int G_KE  = 393216, G_VE   = 524288;

    CvtArgs ca;
    ca.d[0] = {l_qkv_w,  wts + L_QKV,  49152, 0};
    ca.d[1] = {l_proj_w, wts + L_PROJ, 16384, 0};
    ca.d[2] = {l_fc1_w,  wts + L_FC1,  65536, 0};
    ca.d[3] = {l_fc2_w,  wts + L_FC2,  65536, 0};
    ca.d[4] = {g_qkv_w,  wts + G_QKV,  49152, 0};
    ca.d[5] = {g_proj_w, wts + G_PROJ, 16384, 0};
    ca.d[6] = {g_fc1_w,  wts + G_FC1,  65536, 0};
    ca.d[7] = {g_fc2_w,  wts + G_FC2,  65536, 0};
    ca.d[8] = {g_ke_w,   wts + G_KE,  131072, 0};
    ca.d[9] = {g_ve_w,   wts + G_VE,  131072, 0};

    // 1-3: preamble (round-6 structure: massively parallel, known-good)
    cvtw_k<<<dim3(32, 10), 256, 0, stream>>>(ca);
    transpose_k<<<dim3(256, 4), dim3(32, 8), 0, stream>>>(x, xt);
    ln_token_k<<<2048, 256, 0, stream>>>(xt, l_n1_g, l_n1_b, yA16, g_n1_g, g_n1_b, yG16);

    // 4: both qkv GEMMs
    MArgs a_qkv = {{yA16, yG16}, {wts + L_QKV, wts + G_QKV}, {nullptr, nullptr}, {nullptr, nullptr}, {qkv_l, qkv_g}};
    mgemm_k<0><<<dim3(64, 3, 2), 256, 0, stream>>>(a_qkv, N_TOK, 384, 128, 0);

    // 5-6: local attention; global gather
    local_attn_k<<<256, dim3(32, 8), 0, stream>>>(qkv_l, obuf_l);
    gather_k<<<4096, 256, 0, stream>>>(qkv_g, kg16, vg16);

    // 7: both conv reductions, split-K x8
    MArgs a_cv = {{kg16, vg16}, {wts + G_KE, wts + G_VE}, {nullptr, nullptr}, {nullptr, nullptr}, {kpart, vpart}};
    mgemm_k<3><<<dim3(8, 1, 16), 256, 0, stream>>>(a_cv, NR, 128, 1024, 128);

    // 8: head-LN for K (scaled for exp2) and V^T
    ln_head_sum_k<<<64, 256, 0, stream>>>(kpart, vpart, g_nk_g, g_nk_b, g_nv_g, g_nv_b, kb16, vt16);

    // 9: global attention (MFMA flash v7)
    gattn_k<<<dim3(128, 8), 256, 0, stream>>>(qkv_g, kb16, vt16, obuf_g);

    // 10: both proj GEMMs (+bias+residual)
    MArgs a_pj = {{obuf_l, obuf_g}, {wts + L_PROJ, wts + G_PROJ}, {l_proj_b, g_proj_b}, {xt, xt}, {t1_l, t1_g}};
    mgemm_k<1><<<dim3(64, 1, 2), 256, 0, stream>>>(a_pj, N_TOK, 128, 128, 0);

    // 11: both second LNs
    ln2_pair_k<<<4096, 256, 0, stream>>>(t1_l, l_n2_g, l_n2_b, t2_l, t1_g, g_n2_g, g_n2_b, t2_g);

    // 12: both fc1 GEMMs (+bias+gelu)
    MArgs a_f1 = {{t2_l, t2_g}, {wts + L_FC1, wts + G_FC1}, {l_fc1_b, g_fc1_b}, {nullptr, nullptr}, {h1_l, h1_g}};
    mgemm_k<2><<<dim3(64, 4, 2), 256, 0, stream>>>(a_f1, N_TOK, 512, 128, 0);

    // 13: both fc2 GEMMs (+bias+residual)
    MArgs a_f2 = {{h1_l, h1_g}, {wts + L_FC2, wts + G_FC2}, {l_fc2_b, g_fc2_b}, {t1_l, t1_g}, {locfin, glofin}};
    mgemm_k<1><<<dim3(64, 1, 2), 256, 0, stream>>>(a_f2, N_TOK, 128, 512, 0);

    // 14: gate
    gate_k<<<dim3(256, 4), dim3(32, 8), 0, stream>>>(x, locfin, glofin, out);
}

// Round 9
// 141.305 us; speedup vs baseline: 1.1101x; 1.0190x over previous
//
#include <hip/hip_runtime.h>
#include <math.h>

#define N_TOK 8192
#define C_DIM 128
#define NHD   8
#define HDIM  16
#define NR    1024
#define EPSV  1e-5f
#define QK_SCALE 0.25f
#define QK_L2E  0.36067376f   /* 0.25 * log2(e) */

typedef __attribute__((ext_vector_type(8))) short short8;
typedef __attribute__((ext_vector_type(4))) float f32x4;

__device__ __forceinline__ float gelu_f(float v) {
    return 0.5f * v * (1.0f + erff(v * 0.70710678118654752f));
}
__device__ __forceinline__ float uaf(unsigned int u) {
    union { unsigned int u; float f; } x; x.u = u; return x.f;
}
__device__ __forceinline__ short f2b(float v) {
    union { float f; unsigned int u; } x; x.f = v;
    unsigned int r = x.u + 0x7fffu + ((x.u >> 16) & 1u);
    return (short)(r >> 16);
}
__device__ __forceinline__ void ld16bf(const short* p, float* d) {
    uint4 a = *(const uint4*)p;
    uint4 b = *(const uint4*)(p + 8);
    d[0]  = uaf(a.x << 16); d[1]  = uaf(a.x & 0xffff0000u);
    d[2]  = uaf(a.y << 16); d[3]  = uaf(a.y & 0xffff0000u);
    d[4]  = uaf(a.z << 16); d[5]  = uaf(a.z & 0xffff0000u);
    d[6]  = uaf(a.w << 16); d[7]  = uaf(a.w & 0xffff0000u);
    d[8]  = uaf(b.x << 16); d[9]  = uaf(b.x & 0xffff0000u);
    d[10] = uaf(b.y << 16); d[11] = uaf(b.y & 0xffff0000u);
    d[12] = uaf(b.z << 16); d[13] = uaf(b.z & 0xffff0000u);
    d[14] = uaf(b.w << 16); d[15] = uaf(b.w & 0xffff0000u);
}

struct CvtDesc { const float* src; short* dst; int n; int pad; };
struct CvtArgs { CvtDesc d[10]; };

// ------- fused (partition): transpose (blocks 0..1023, unchanged) + weight cvt ------
// cvt with pad=1 permutes conv weights [co][ci*8+off] -> [co][off*128+ci]
__global__ __launch_bounds__(256) void cvtrans_k(const float* __restrict__ x,
                                                 float* __restrict__ xt, CvtArgs ca) {
    __shared__ float tile[32][33];
    int t = threadIdx.x;
    if (blockIdx.x < 1024) {
        int bx = blockIdx.x & 255, by = blockIdx.x >> 8;
        int tx = t & 31, ty = t >> 5;
        int n0 = bx * 32, c0 = by * 32;
#pragma unroll
        for (int k = 0; k < 4; ++k)
            tile[ty + k * 8][tx] = x[(size_t)(c0 + ty + k * 8) * N_TOK + n0 + tx];
        __syncthreads();
#pragma unroll
        for (int k = 0; k < 4; ++k)
            xt[(size_t)(n0 + ty + k * 8) * C_DIM + c0 + tx] = tile[tx][ty + k * 8];
        return;
    }
    int bid = blockIdx.x - 1024;   // 0..39
#pragma unroll 1
    for (int d = 0; d < 10; ++d) {
        CvtDesc dd = ca.d[d];
        if (dd.pad) {
            for (int i = bid * 256 + t; i < dd.n; i += 40 * 256) {
                int co = i >> 10, qq = i & 1023;
                dd.dst[co * 1024 + ((qq & 7) << 7) + (qq >> 3)] = f2b(dd.src[i]);
            }
        } else {
            for (int i = bid * 256 + t; i < dd.n; i += 40 * 256)
                dd.dst[i] = f2b(dd.src[i]);
        }
    }
}

// ---------------- first LN: fp32 in, two bf16 outputs ----------------
__global__ __launch_bounds__(256) void ln_token_k(const float* __restrict__ in,
                                                  const float* __restrict__ g1, const float* __restrict__ b1,
                                                  short* __restrict__ o1,
                                                  const float* __restrict__ g2, const float* __restrict__ b2,
                                                  short* __restrict__ o2) {
    int lane = threadIdx.x & 63;
    int n = blockIdx.x * 4 + (threadIdx.x >> 6);
    float v0 = in[(size_t)n * C_DIM + lane];
    float v1 = in[(size_t)n * C_DIM + 64 + lane];
    float s = v0 + v1, sq = v0 * v0 + v1 * v1;
#pragma unroll
    for (int off = 32; off >= 1; off >>= 1) {
        s += __shfl_xor(s, off);
        sq += __shfl_xor(sq, off);
    }
    float m = s * (1.0f / 128.0f);
    float var = sq * (1.0f / 128.0f) - m * m;
    float rs = rsqrtf(var + EPSV);
    float h0 = (v0 - m) * rs, h1 = (v1 - m) * rs;
    o1[(size_t)n * C_DIM + lane]      = f2b(h0 * g1[lane] + b1[lane]);
    o1[(size_t)n * C_DIM + 64 + lane] = f2b(h1 * g1[lane + 64] + b1[lane + 64]);
    o2[(size_t)n * C_DIM + lane]      = f2b(h0 * g2[lane] + b2[lane]);
    o2[(size_t)n * C_DIM + 64 + lane] = f2b(h1 * g2[lane + 64] + b2[lane + 64]);
}

// ---------------- second LN, paired across branches ----------------
__global__ __launch_bounds__(256) void ln2_pair_k(const float* __restrict__ in0,
                                                  const float* __restrict__ g0, const float* __restrict__ b0,
                                                  short* __restrict__ o0,
                                                  const float* __restrict__ in1,
                                                  const float* __restrict__ g1, const float* __restrict__ b1,
                                                  short* __restrict__ o1) {
    int blk = blockIdx.x;
    bool sel = blk >= 2048;
    blk &= 2047;
    const float* in = sel ? in1 : in0;
    const float* g  = sel ? g1 : g0;
    const float* b  = sel ? b1 : b0;
    short* o        = sel ? o1 : o0;
    int lane = threadIdx.x & 63;
    int n = blk * 4 + (threadIdx.x >> 6);
    float v0 = in[(size_t)n * C_DIM + lane];
    float v1 = in[(size_t)n * C_DIM + 64 + lane];
    float s = v0 + v1, sq = v0 * v0 + v1 * v1;
#pragma unroll
    for (int off = 32; off >= 1; off >>= 1) {
        s += __shfl_xor(s, off);
        sq += __shfl_xor(sq, off);
    }
    float m = s * (1.0f / 128.0f);
    float var = sq * (1.0f / 128.0f) - m * m;
    float rs = rsqrtf(var + EPSV);
    o[(size_t)n * C_DIM + lane]      = f2b((v0 - m) * rs * g[lane] + b[lane]);
    o[(size_t)n * C_DIM + 64 + lane] = f2b((v1 - m) * rs * g[lane + 64] + b[lane + 64]);
}

// ---------------- bf16 MFMA GEMM, branch-paired via blockIdx.z ----------------
// EPI: 0 bf16 out; 1 f32 = acc+bias+res; 2 bf16 = gelu(acc+bias)
struct MArgs {
    const short* A[2]; const short* W[2];
    const float* bias[2]; const float* res[2];
    void* out[2];
};
template <int EPI>
__global__ __launch_bounds__(256) void mgemm_k(MArgs ga, int M, int N, int K) {
    int zi = blockIdx.z;
    const short* A = ga.A[zi];
    const short* W = ga.W[zi];
    __shared__ short As[128 * 64];
    __shared__ short Bs[128 * 64];
    int t = threadIdx.x;
    int w = t >> 6, l = t & 63;
    int m0 = blockIdx.x * 128, n0 = blockIdx.y * 128;
    int wm = (w >> 1) * 64, wn = (w & 1) * 64;

    f32x4 acc[4][4];
#pragma unroll
    for (int a = 0; a < 4; ++a)
#pragma unroll
        for (int b = 0; b < 4; ++b) acc[a][b] = f32x4{0.f, 0.f, 0.f, 0.f};

    for (int k0 = 0; k0 < K; k0 += 64) {
        __syncthreads();
#pragma unroll
        for (int c = 0; c < 4; ++c) {
            int chunk = c * 256 + t;
            int row = chunk >> 3;
            int slot = chunk & 7;
            int ss = slot ^ (row & 7);
            uint4 av = *(const uint4*)(A + (size_t)(m0 + row) * K + k0 + slot * 8);
            *(uint4*)(As + row * 64 + ss * 8) = av;
            uint4 wv = *(const uint4*)(W + (size_t)(n0 + row) * K + k0 + slot * 8);
            *(uint4*)(Bs + row * 64 + ss * 8) = wv;
        }
        __syncthreads();
#pragma unroll
        for (int kk = 0; kk < 2; ++kk) {
            short8 af[4], bf[4];
            int sl = kk * 4 + (l >> 4);
#pragma unroll
            for (int mf = 0; mf < 4; ++mf) {
                int row = wm + mf * 16 + (l & 15);
                af[mf] = *(const short8*)(As + row * 64 + (sl ^ (row & 7)) * 8);
            }
#pragma unroll
            for (int nf = 0; nf < 4; ++nf) {
                int row = wn + nf * 16 + (l & 15);
                bf[nf] = *(const short8*)(Bs + row * 64 + (sl ^ (row & 7)) * 8);
            }
#pragma unroll
            for (int mf = 0; mf < 4; ++mf)
#pragma unroll
                for (int nf = 0; nf < 4; ++nf)
                    acc[mf][nf] = __builtin_amdgcn_mfma_f32_16x16x32_bf16(
                        af[mf], bf[nf], acc[mf][nf], 0, 0, 0);
        }
    }

#pragma unroll
    for (int mf = 0; mf < 4; ++mf) {
#pragma unroll
        for (int nf = 0; nf < 4; ++nf) {
            int col = n0 + wn + nf * 16 + (l & 15);
#pragma unroll
            for (int j = 0; j < 4; ++j) {
                int row = m0 + wm + mf * 16 + (l >> 4) * 4 + j;
                float v = acc[mf][nf][j];
                if (EPI == 0) {
                    ((short*)ga.out[zi])[(size_t)row * N + col] = f2b(v);
                } else if (EPI == 1) {
                    v += ga.bias[zi][col] + ga.res[zi][(size_t)row * N + col];
                    ((float*)ga.out[zi])[(size_t)row * N + col] = v;
                } else if (EPI == 2) {
                    v = gelu_f(v + ga.bias[zi][col]);
                    ((short*)ga.out[zi])[(size_t)row * N + col] = f2b(v);
                }
            }
        }
    }
}

// ------- fused: conv reductions w/ inline gather (blocks 0..127) + local attention --
// conv: A streamed directly from qkv_g (off-major K), W pre-permuted; split-K x8.
struct CLArgs {
    const short* qkv_g; const short* wk; const short* wv;
    float* kpart; float* vpart;
    const short* qkv_l; short* ob;
};
__global__ __launch_bounds__(256) void convlat_k(CLArgs ga) {
    __shared__ char smem[32768];
    int t = threadIdx.x;
    if (blockIdx.x < 128) {
        int bid = blockIdx.x;
        int m0 = (bid & 7) * 128;
        int zi = bid >> 6;              // 0 = K-conv, 1 = V-conv
        int slice = (bid >> 3) & 7;     // K-slice (off value)
        const short* Abase = ga.qkv_g + (zi ? 256 : 128);
        const short* W = zi ? ga.wv : ga.wk;
        float* outp = zi ? ga.vpart : ga.kpart;
        short* As = (short*)smem;
        short* Bs = (short*)smem + 128 * 64;
        int w = t >> 6, l = t & 63;
        int wm = (w >> 1) * 64, wn = (w & 1) * 64;
        int kbeg = slice * 128;

        f32x4 acc[4][4];
#pragma unroll
        for (int a = 0; a < 4; ++a)
#pragma unroll
            for (int b = 0; b < 4; ++b) acc[a][b] = f32x4{0.f, 0.f, 0.f, 0.f};

        for (int k0 = kbeg; k0 < kbeg + 128; k0 += 64) {
            __syncthreads();
            int off = k0 >> 7;   // == slice
            int od = off >> 2, oh = (off >> 1) & 1, ow = off & 1;
#pragma unroll
            for (int c = 0; c < 4; ++c) {
                int chunk = c * 256 + t;
                int row = chunk >> 3;
                int slot = chunk & 7;
                int ss = slot ^ (row & 7);
                int nr = m0 + row;
                int ci = (k0 & 127) + slot * 8;
                int n = (2 * (nr >> 8) + od) * 1024 + (2 * ((nr >> 4) & 15) + oh) * 32
                        + 2 * (nr & 15) + ow;
                uint4 av = *(const uint4*)(Abase + (size_t)n * 384 + ci);
                *(uint4*)(As + row * 64 + ss * 8) = av;
                uint4 wv2 = *(const uint4*)(W + (size_t)row * 1024 + k0 + slot * 8);
                *(uint4*)(Bs + row * 64 + ss * 8) = wv2;
            }
            __syncthreads();
#pragma unroll
            for (int kk = 0; kk < 2; ++kk) {
                short8 af[4], bf[4];
                int sl = kk * 4 + (l >> 4);
#pragma unroll
                for (int mf = 0; mf < 4; ++mf) {
                    int row = wm + mf * 16 + (l & 15);
                    af[mf] = *(const short8*)(As + row * 64 + (sl ^ (row & 7)) * 8);
                }
#pragma unroll
                for (int nf = 0; nf < 4; ++nf) {
                    int row = wn + nf * 16 + (l & 15);
                    bf[nf] = *(const short8*)(Bs + row * 64 + (sl ^ (row & 7)) * 8);
                }
#pragma unroll
                for (int mf = 0; mf < 4; ++mf)
#pragma unroll
                    for (int nf = 0; nf < 4; ++nf)
                        acc[mf][nf] = __builtin_amdgcn_mfma_f32_16x16x32_bf16(
                            af[mf], bf[nf], acc[mf][nf], 0, 0, 0);
            }
        }
#pragma unroll
        for (int mf = 0; mf < 4; ++mf)
#pragma unroll
            for (int nf = 0; nf < 4; ++nf) {
                int col = wn + nf * 16 + (l & 15);
#pragma unroll
                for (int j = 0; j < 4; ++j) {
                    int row = m0 + wm + mf * 16 + (l >> 4) * 4 + j;
                    outp[(size_t)slice * (NR * C_DIM) + (size_t)row * C_DIM + col] =
                        acc[mf][nf][j];
                }
            }
        return;
    }
    // ---- local attention blocks (128..383) ----
    float (*ks)[32][HDIM] = (float(*)[32][HDIM])smem;
    float (*vs)[32][HDIM] = (float(*)[32][HDIM])(smem + 16384);
    int m = t & 31, h = t >> 5, r = blockIdx.x - 128;
    int zd = r >> 6, zh = (r >> 3) & 7, zw = r & 7;
    int pd = m >> 4, ph = (m >> 2) & 3, pw = m & 3;
    int n = (zd * 2 + pd) * 1024 + (zh * 4 + ph) * 32 + (zw * 4 + pw);
    const short* base = ga.qkv_l + (size_t)n * 384 + h * HDIM;
    float q[16], kt[16], vt[16];
    ld16bf(base, q);
    ld16bf(base + 128, kt);
    ld16bf(base + 256, vt);
#pragma unroll
    for (int d = 0; d < 16; ++d) { ks[h][m][d] = kt[d]; vs[h][m][d] = vt[d]; }
    __syncthreads();
    float s[32];
#pragma unroll
    for (int j = 0; j < 32; ++j) {
        float d = 0.f;
#pragma unroll
        for (int dd = 0; dd < 16; ++dd) d += q[dd] * ks[h][j][dd];
        s[j] = __expf(d * QK_SCALE);
    }
    float sum = 0.f;
#pragma unroll
    for (int j = 0; j < 32; ++j) sum += s[j];
    float inv = 1.0f / sum;
    float oo[16] = {};
#pragma unroll
    for (int j = 0; j < 32; ++j) {
        float p = s[j] * inv;
#pragma unroll
        for (int dd = 0; dd < 16; ++dd) oo[dd] += p * vs[h][j][dd];
    }
#pragma unroll
    for (int dd = 0; dd < 16; ++dd) {
        int n2 = h * 4 + (dd >> 2);
        int c2 = (dd & 3) * 32 + m;
        int pd2 = n2 >> 4, ph2 = (n2 >> 2) & 3, pw2 = n2 & 3;
        int nn = (zd * 2 + pd2) * 1024 + (zh * 4 + ph2) * 32 + (zw * 4 + pw2);
        ga.ob[(size_t)nn * C_DIM + c2] = f2b(oo[dd]);
    }
}

// ------- sum 8 split-K partials + per-head LN; K -> bf16 *0.25*log2e, V -> bf16^T ---
__global__ __launch_bounds__(256) void ln_head_sum_k(const float* __restrict__ kpart,
                                                     const float* __restrict__ vpart,
                                                     const float* __restrict__ gk, const float* __restrict__ bk,
                                                     const float* __restrict__ gv, const float* __restrict__ bv,
                                                     short* __restrict__ kout, short* __restrict__ vout) {
    int idx = blockIdx.x * 256 + threadIdx.x;   // 0..16383
    bool sel = idx >= 8192;
    int id2 = idx & 8191;
    const float* part = sel ? vpart : kpart;
    const float* g    = sel ? gv : gk;
    const float* b    = sel ? bv : bk;
    int nr = id2 >> 3, h = id2 & 7;
    size_t base = (size_t)nr * C_DIM + h * HDIM;
    float v[16] = {};
#pragma unroll
    for (int p = 0; p < 8; ++p) {
        const float* pp = part + (size_t)p * (NR * C_DIM) + base;
#pragma unroll
        for (int d4 = 0; d4 < 4; ++d4) {
            float4 t = *(const float4*)(pp + d4 * 4);
            v[d4 * 4 + 0] += t.x; v[d4 * 4 + 1] += t.y;
            v[d4 * 4 + 2] += t.z; v[d4 * 4 + 3] += t.w;
        }
    }
    float s = 0.f;
#pragma unroll
    for (int i = 0; i < 16; ++i) s += v[i];
    float m = s * (1.0f / 16.0f);
    float sq = 0.f;
#pragma unroll
    for (int i = 0; i < 16; ++i) { float d = v[i] - m; sq += d * d; }
    float rs = rsqrtf(sq * (1.0f / 16.0f) + EPSV);
    if (!sel) {
        short* op = kout + (size_t)h * (NR * HDIM) + (size_t)nr * HDIM;
#pragma unroll
        for (int i = 0; i < 16; ++i)
            op[i] = f2b(((v[i] - m) * rs * g[i] + b[i]) * QK_L2E);
    } else {
        short* op = vout + (size_t)h * (HDIM * NR) + nr;
#pragma unroll
        for (int i = 0; i < 16; ++i)
            op[(size_t)i * NR] = f2b((v[i] - m) * rs * g[i] + b[i]);
    }
}

// ---------------- global attention v7: swapped QK^T, cvt_pk paired P stores --------
__global__ __launch_bounds__(256) void gattn_k(const short* __restrict__ qkv,
                                               const short* __restrict__ kb,   // [8][1024][16] *0.25*log2e
                                               const short* __restrict__ vt,   // [8][16][1024]
                                               short* __restrict__ ob) {
    __shared__ short plds[4][2048];
    int t = threadIdx.x;
    int w = t >> 6, l = t & 63;
    int h = blockIdx.y;
    int lr = l & 15, lq = l >> 4;
    int q0 = blockIdx.x * 64 + w * 16;

    short8 qf = short8{0, 0, 0, 0, 0, 0, 0, 0};
    if (lq < 2)
        qf = *(const short8*)(qkv + (size_t)(q0 + lr) * 384 + h * HDIM + lq * 8);

    const short* kh = kb + (size_t)h * (NR * HDIM);
    const short* vh = vt + (size_t)h * (HDIM * NR);
    short* pw = &plds[w][0];

    const f32x4 zz = {0.f, 0.f, 0.f, 0.f};
    f32x4 oacc = {0.f, 0.f, 0.f, 0.f};
    float rs = 0.f;

    for (int c = 0; c < 8; ++c) {
        int kbase = c * 128;
        f32x4 s[8];
#pragma unroll
        for (int nf = 0; nf < 8; ++nf) {
            short8 kf = short8{0, 0, 0, 0, 0, 0, 0, 0};
            if (lq < 2)
                kf = *(const short8*)(kh + (size_t)(kbase + nf * 16 + lr) * HDIM + lq * 8);
            s[nf] = __builtin_amdgcn_mfma_f32_16x16x32_bf16(kf, qf, zz, 0, 0, 0);
        }
#pragma unroll
        for (int nf = 0; nf < 8; ++nf) {
            float p0 = exp2f(s[nf][0]);
            float p1 = exp2f(s[nf][1]);
            float p2 = exp2f(s[nf][2]);
            float p3 = exp2f(s[nf][3]);
            rs += (p0 + p1) + (p2 + p3);
            unsigned int u01, u23;
            asm("v_cvt_pk_bf16_f32 %0, %1, %2" : "=v"(u01) : "v"(p0), "v"(p1));
            asm("v_cvt_pk_bf16_f32 %0, %1, %2" : "=v"(u23) : "v"(p2), "v"(p3));
            int k0 = nf * 16 + lq * 4;
            int sw = (lr & 7) << 3;
            *(unsigned int*)&pw[lr * 128 + (k0 ^ sw)]       = u01;
            *(unsigned int*)&pw[lr * 128 + ((k0 + 2) ^ sw)] = u23;
        }
#pragma unroll
        for (int ks = 0; ks < 4; ++ks) {
            short8 pf = *(const short8*)&pw[(lr * 128 + ks * 32 + lq * 8) ^ ((lr & 7) << 3)];
            short8 vf = *(const short8*)(vh + (size_t)lr * NR + kbase + ks * 32 + lq * 8);
            oacc = __builtin_amdgcn_mfma_f32_16x16x32_bf16(pf, vf, oacc, 0, 0, 0);
        }
    }
    rs += __shfl_xor(rs, 16);
    rs += __shfl_xor(rs, 32);
    float r0 = __shfl(rs, lq * 4 + 0);
    float r1 = __shfl(rs, lq * 4 + 1);
    float r2 = __shfl(rs, lq * 4 + 2);
    float r3 = __shfl(rs, lq * 4 + 3);
    size_t base_o = (size_t)(q0 + lq * 4) * C_DIM + h * HDIM + lr;
    ob[base_o]             = f2b(oacc[0] / r0);
    ob[base_o + C_DIM]     = f2b(oacc[1] / r1);
    ob[base_o + 2 * C_DIM] = f2b(oacc[2] / r2);
    ob[base_o + 3 * C_DIM] = f2b(oacc[3] / r3);
}

// ---------------- final gate: out(C,N) = x * sigmoid(loc + glo) ----------------
__global__ __launch_bounds__(256) void gate_k(const float* __restrict__ x,
                                              const float* __restrict__ lf, const float* __restrict__ gf,
                                              float* __restrict__ out) {
    __shared__ float tile[32][33];
    int n0 = blockIdx.x * 32, c0 = blockIdx.y * 32;
    int tx = threadIdx.x, ty = threadIdx.y;
#pragma unroll
    for (int k = 0; k < 4; ++k) {
        int n = n0 + ty + k * 8, c = c0 + tx;
        tile[ty + k * 8][tx] = lf[(size_t)n * C_DIM + c] + gf[(size_t)n * C_DIM + c];
    }
    __syncthreads();
#pragma unroll
    for (int k = 0; k < 4; ++k) {
        int c = c0 + ty + k * 8, n = n0 + tx;
        float z = tile[tx][ty + k * 8];
        float sg = 1.0f / (1.0f + __expf(-z));
        out[(size_t)c * N_TOK + n] = x[(size_t)c * N_TOK + n] * sg;
    }
}

extern "C" void kernel_launch(void* const* d_in, const int* in_sizes, int n_in,
                              void* d_out, int out_size, void* d_ws, size_t ws_size,
                              hipStream_t stream) {
    const float* x        = (const float*)d_in[0];
    const float* l_n1_g   = (const float*)d_in[1];
    const float* l_n1_b   = (const float*)d_in[2];
    const float* l_qkv_w  = (const float*)d_in[3];
    const float* l_proj_w = (const float*)d_in[4];
    const float* l_proj_b = (const float*)d_in[5];
    const float* l_n2_g   = (const float*)d_in[6];
    const float* l_n2_b   = (const float*)d_in[7];
    const float* l_fc1_w  = (const float*)d_in[8];
    const float* l_fc1_b  = (const float*)d_in[9];
    const float* l_fc2_w  = (const float*)d_in[10];
    const float* l_fc2_b  = (const float*)d_in[11];
    const float* g_n1_g   = (const float*)d_in[12];
    const float* g_n1_b   = (const float*)d_in[13];
    const float* g_qkv_w  = (const float*)d_in[14];
    const float* g_proj_w = (const float*)d_in[15];
    const float* g_proj_b = (const float*)d_in[16];
    const float* g_n2_g   = (const float*)d_in[17];
    const float* g_n2_b   = (const float*)d_in[18];
    const float* g_fc1_w  = (const float*)d_in[19];
    const float* g_fc1_b  = (const float*)d_in[20];
    const float* g_fc2_w  = (const float*)d_in[21];
    const float* g_fc2_b  = (const float*)d_in[22];
    const float* g_ke_w   = (const float*)d_in[23];
    const float* g_ve_w   = (const float*)d_in[24];
    const float* g_nk_g   = (const float*)d_in[25];
    const float* g_nk_b   = (const float*)d_in[26];
    const float* g_nv_g   = (const float*)d_in[27];
    const float* g_nv_b   = (const float*)d_in[28];
    float* out = (float*)d_out;

    char* base = (char*)d_ws;
    float* xt     = (float*)(base);                        // 0-4 MB
    float* t1_l   = (float*)(base + (4ull  << 20));        // 4-8 MB
    float* t1_g   = (float*)(base + (8ull  << 20));        // 8-12 MB
    short* yA16   = (short*)(base + (12ull << 20));        // 12-14 (later t2_l)
    short* yG16   = (short*)(base + (14ull << 20));        // 14-16 (later t2_g)
    short* t2_l   = yA16;
    short* t2_g   = yG16;
    float* locfin = (float*)(base + (12ull << 20));        // 12-16 (after fc1 reads t2)
    short* obuf_l = (short*)(base + (16ull << 20));        // 16-18
    short* obuf_g = (short*)(base + (18ull << 20));        // 18-20
    float* glofin = (float*)(base + (16ull << 20));        // 16-20 (after proj reads obuf)
    short* qkv_l  = (short*)(base + (20ull << 20));        // 20-26
    short* qkv_g  = (short*)(base + (26ull << 20));        // 26-32
    short* h1_l   = (short*)(base + (32ull << 20));        // 32-40 (after ln_head)
    float* kpart  = (float*)(base + (32ull << 20));        // 32-36 (pre-fc1)
    float* vpart  = (float*)(base + (36ull << 20));        // 36-40 (pre-fc1)
    short* h1_g   = (short*)(base + (40ull << 20));        // 40-48
    short* kb16   = (short*)(base + (48ull << 20));        // [8][1024][16]
    short* vt16   = (short*)(base + (48ull << 20) + (512ull << 10)); // [8][16][1024]
    short* wts    = (short*)(base + (49ull << 20));        // ~1.3 MB

    const int L_QKV = 0,      L_PROJ = 49152, L_FC1 = 65536,  L_FC2 = 131072;
    const int G_QKV = 196608, G_PROJ = 245760, G_FC1 = 262144, G_FC2 = 327680;
    const int G_KE  = 393216, G_VE   = 524288;

    CvtArgs ca;
    ca.d[0] = {l_qkv_w,  wts + L_QKV,  49152, 0};
    ca.d[1] = {l_proj_w, wts + L_PROJ, 16384, 0};
    ca.d[2] = {l_fc1_w,  wts + L_FC1,  65536, 0};
    ca.d[3] = {l_fc2_w,  wts + L_FC2,  65536, 0};
    ca.d[4] = {g_qkv_w,  wts + G_QKV,  49152, 0};
    ca.d[5] = {g_proj_w, wts + G_PROJ, 16384, 0};
    ca.d[6] = {g_fc1_w,  wts + G_FC1,  65536, 0};
    ca.d[7] = {g_fc2_w,  wts + G_FC2,  65536, 0};
    ca.d[8] = {g_ke_w,   wts + G_KE,  131072, 1};   // permuted: [co][off*128+ci]
    ca.d[9] = {g_ve_w,   wts + G_VE,  131072, 1};

    // 1: transpose + weight cvt (fused, partition)
    cvtrans_k<<<1064, 256, 0, stream>>>(x, xt, ca);

    // 2: first LN (both gamma/beta sets)
    ln_token_k<<<2048, 256, 0, stream>>>(xt, l_n1_g, l_n1_b, yA16, g_n1_g, g_n1_b, yG16);

    // 3: both qkv GEMMs
    MArgs a_qkv = {{yA16, yG16}, {wts + L_QKV, wts + G_QKV}, {nullptr, nullptr}, {nullptr, nullptr}, {qkv_l, qkv_g}};
    mgemm_k<0><<<dim3(64, 3, 2), 256, 0, stream>>>(a_qkv, N_TOK, 384, 128);

    // 4: conv reductions (inline gather, split-K x8) + local attention (fused)
    CLArgs cla = {qkv_g, wts + G_KE, wts + G_VE, kpart, vpart, qkv_l, obuf_l};
    convlat_k<<<384, 256, 0, stream>>>(cla);

    // 5: head-LN for K (scaled for exp2) and V^T
    ln_head_sum_k<<<64, 256, 0, stream>>>(kpart, vpart, g_nk_g, g_nk_b, g_nv_g, g_nv_b, kb16, vt16);

    // 6: global attention (MFMA flash v7)
    gattn_k<<<dim3(128, 8), 256, 0, stream>>>(qkv_g, kb16, vt16, obuf_g);

    // 7: both proj GEMMs (+bias+residual)
    MArgs a_pj = {{obuf_l, obuf_g}, {wts + L_PROJ, wts + G_PROJ}, {l_proj_b, g_proj_b}, {xt, xt}, {t1_l, t1_g}};
    mgemm_k<1><<<dim3(64, 1, 2), 256, 0, stream>>>(a_pj, N_TOK, 128, 128);

    // 8: both second LNs
    ln2_pair_k<<<4096, 256, 0, stream>>>(t1_l, l_n2_g, l_n2_b, t2_l, t1_g, g_n2_g, g_n2_b, t2_g);

    // 9: both fc1 GEMMs (+bias+gelu)
    MArgs a_f1 = {{t2_l, t2_g}, {wts + L_FC1, wts + G_FC1}, {l_fc1_b, g_fc1_b}, {nullptr, nullptr}, {h1_l, h1_g}};
    mgemm_k<2><<<dim3(64, 4, 2), 256, 0, stream>>>(a_f1, N_TOK, 512, 128);

    // 10: both fc2 GEMMs (+bias+residual)
    MArgs a_f2 = {{h1_l, h1_g}, {wts + L_FC2, wts + G_FC2}, {l_fc2_b, g_fc2_b}, {t1_l, t1_g}, {locfin, glofin}};
    mgemm_k<1><<<dim3(64, 1, 2), 256, 0, stream>>>(a_f2, N_TOK, 128, 512);

    // 11: gate
    gate_k<<<dim3(256, 4), dim3(32, 8), 0, stream>>>(x, locfin, glofin, out);
}

// Round 10
// 140.729 us; speedup vs baseline: 1.1147x; 1.0041x over previous
//
#include <hip/hip_runtime.h>
#include <math.h>

#define N_TOK 8192
#define C_DIM 128
#define NHD   8
#define HDIM  16
#define NR    1024
#define EPSV  1e-5f
#define QK_SCALE 0.25f
#define QK_L2E  0.36067376f   /* 0.25 * log2(e) */

typedef __attribute__((ext_vector_type(8))) short short8;
typedef __attribute__((ext_vector_type(4))) float f32x4;

__device__ __forceinline__ float gelu_f(float v) {
    return 0.5f * v * (1.0f + erff(v * 0.70710678118654752f));
}
__device__ __forceinline__ float uaf(unsigned int u) {
    union { unsigned int u; float f; } x; x.u = u; return x.f;
}
__device__ __forceinline__ short f2b(float v) {
    union { float f; unsigned int u; } x; x.f = v;
    unsigned int r = x.u + 0x7fffu + ((x.u >> 16) & 1u);
    return (short)(r >> 16);
}
__device__ __forceinline__ unsigned int pk2(float a, float b) {
    return (unsigned int)(unsigned short)f2b(a) | ((unsigned int)(unsigned short)f2b(b) << 16);
}
__device__ __forceinline__ void ld16bf(const short* p, float* d) {
    uint4 a = *(const uint4*)p;
    uint4 b = *(const uint4*)(p + 8);
    d[0]  = uaf(a.x << 16); d[1]  = uaf(a.x & 0xffff0000u);
    d[2]  = uaf(a.y << 16); d[3]  = uaf(a.y & 0xffff0000u);
    d[4]  = uaf(a.z << 16); d[5]  = uaf(a.z & 0xffff0000u);
    d[6]  = uaf(a.w << 16); d[7]  = uaf(a.w & 0xffff0000u);
    d[8]  = uaf(b.x << 16); d[9]  = uaf(b.x & 0xffff0000u);
    d[10] = uaf(b.y << 16); d[11] = uaf(b.y & 0xffff0000u);
    d[12] = uaf(b.z << 16); d[13] = uaf(b.z & 0xffff0000u);
    d[14] = uaf(b.w << 16); d[15] = uaf(b.w & 0xffff0000u);
}

struct CvtDesc { const float* src; short* dst; int n; int pad; };
struct CvtArgs { CvtDesc d[10]; };

// ------- fused: transpose+LN1 (blocks 0..255, 32 tokens each) + weight cvt ----------
__global__ __launch_bounds__(256) void prep_k(const float* __restrict__ x,
                                              const float* __restrict__ g1, const float* __restrict__ b1,
                                              const float* __restrict__ g2, const float* __restrict__ b2,
                                              float* __restrict__ xt,
                                              short* __restrict__ o1, short* __restrict__ o2,
                                              CvtArgs ca) {
    __shared__ float tile[32][132];
    int t = threadIdx.x;
    if (blockIdx.x >= 256) {
        int bid = blockIdx.x - 256;   // 0..39
#pragma unroll 1
        for (int d = 0; d < 10; ++d) {
            CvtDesc dd = ca.d[d];
            if (dd.pad) {
                for (int i = bid * 256 + t; i < dd.n; i += 40 * 256) {
                    int co = i >> 10, qq = i & 1023;
                    dd.dst[co * 1024 + ((qq & 7) << 7) + (qq >> 3)] = f2b(dd.src[i]);
                }
            } else {
                for (int i = bid * 256 + t; i < dd.n; i += 40 * 256)
                    dd.dst[i] = f2b(dd.src[i]);
            }
        }
        return;
    }
    int n0 = blockIdx.x * 32;
#pragma unroll
    for (int k = 0; k < 16; ++k) {
        int f = t + k * 256;
        int n = f & 31, c = f >> 5;
        tile[n][c] = x[(size_t)c * N_TOK + n0 + n];
    }
    __syncthreads();
    int tk = t >> 3, cb = (t & 7) * 16;
    float v[16];
    float s = 0.f, sq = 0.f;
#pragma unroll
    for (int i = 0; i < 16; ++i) {
        v[i] = tile[tk][cb + i];
        s += v[i]; sq += v[i] * v[i];
    }
    s += __shfl_xor(s, 1);  s += __shfl_xor(s, 2);  s += __shfl_xor(s, 4);
    sq += __shfl_xor(sq, 1); sq += __shfl_xor(sq, 2); sq += __shfl_xor(sq, 4);
    float m = s * (1.0f / 128.0f);
    float var = sq * (1.0f / 128.0f) - m * m;
    float rs = rsqrtf(var + EPSV);
    int tok = n0 + tk;
    float* xp = xt + (size_t)tok * C_DIM + cb;
    *(float4*)(xp)      = make_float4(v[0], v[1], v[2], v[3]);
    *(float4*)(xp + 4)  = make_float4(v[4], v[5], v[6], v[7]);
    *(float4*)(xp + 8)  = make_float4(v[8], v[9], v[10], v[11]);
    *(float4*)(xp + 12) = make_float4(v[12], v[13], v[14], v[15]);
    float hA[16], hB[16];
#pragma unroll
    for (int i = 0; i < 16; ++i) {
        float hn = (v[i] - m) * rs;
        hA[i] = hn * g1[cb + i] + b1[cb + i];
        hB[i] = hn * g2[cb + i] + b2[cb + i];
    }
    uint4 ua0 = {pk2(hA[0], hA[1]), pk2(hA[2], hA[3]), pk2(hA[4], hA[5]), pk2(hA[6], hA[7])};
    uint4 ua1 = {pk2(hA[8], hA[9]), pk2(hA[10], hA[11]), pk2(hA[12], hA[13]), pk2(hA[14], hA[15])};
    uint4 ub0 = {pk2(hB[0], hB[1]), pk2(hB[2], hB[3]), pk2(hB[4], hB[5]), pk2(hB[6], hB[7])};
    uint4 ub1 = {pk2(hB[8], hB[9]), pk2(hB[10], hB[11]), pk2(hB[12], hB[13]), pk2(hB[14], hB[15])};
    *(uint4*)(o1 + (size_t)tok * C_DIM + cb)     = ua0;
    *(uint4*)(o1 + (size_t)tok * C_DIM + cb + 8) = ua1;
    *(uint4*)(o2 + (size_t)tok * C_DIM + cb)     = ub0;
    *(uint4*)(o2 + (size_t)tok * C_DIM + cb + 8) = ub1;
}

// ---------------- second LN, paired across branches ----------------
__global__ __launch_bounds__(256) void ln2_pair_k(const float* __restrict__ in0,
                                                  const float* __restrict__ g0, const float* __restrict__ b0,
                                                  short* __restrict__ o0,
                                                  const float* __restrict__ in1,
                                                  const float* __restrict__ g1, const float* __restrict__ b1,
                                                  short* __restrict__ o1) {
    int blk = blockIdx.x;
    bool sel = blk >= 2048;
    blk &= 2047;
    const float* in = sel ? in1 : in0;
    const float* g  = sel ? g1 : g0;
    const float* b  = sel ? b1 : b0;
    short* o        = sel ? o1 : o0;
    int lane = threadIdx.x & 63;
    int n = blk * 4 + (threadIdx.x >> 6);
    float v0 = in[(size_t)n * C_DIM + lane];
    float v1 = in[(size_t)n * C_DIM + 64 + lane];
    float s = v0 + v1, sq = v0 * v0 + v1 * v1;
#pragma unroll
    for (int off = 32; off >= 1; off >>= 1) {
        s += __shfl_xor(s, off);
        sq += __shfl_xor(sq, off);
    }
    float m = s * (1.0f / 128.0f);
    float var = sq * (1.0f / 128.0f) - m * m;
    float rs = rsqrtf(var + EPSV);
    o[(size_t)n * C_DIM + lane]      = f2b((v0 - m) * rs * g[lane] + b[lane]);
    o[(size_t)n * C_DIM + 64 + lane] = f2b((v1 - m) * rs * g[lane + 64] + b[lane + 64]);
}

// ---------------- bf16 MFMA GEMM, branch-paired via blockIdx.z ----------------
struct MArgs {
    const short* A[2]; const short* W[2];
    const float* bias[2]; const float* res[2];
    void* out[2];
};
template <int EPI>
__global__ __launch_bounds__(256) void mgemm_k(MArgs ga, int M, int N, int K) {
    int zi = blockIdx.z;
    const short* A = ga.A[zi];
    const short* W = ga.W[zi];
    __shared__ short As[128 * 64];
    __shared__ short Bs[128 * 64];
    int t = threadIdx.x;
    int w = t >> 6, l = t & 63;
    int m0 = blockIdx.x * 128, n0 = blockIdx.y * 128;
    int wm = (w >> 1) * 64, wn = (w & 1) * 64;

    f32x4 acc[4][4];
#pragma unroll
    for (int a = 0; a < 4; ++a)
#pragma unroll
        for (int b = 0; b < 4; ++b) acc[a][b] = f32x4{0.f, 0.f, 0.f, 0.f};

    for (int k0 = 0; k0 < K; k0 += 64) {
        __syncthreads();
#pragma unroll
        for (int c = 0; c < 4; ++c) {
            int chunk = c * 256 + t;
            int row = chunk >> 3;
            int slot = chunk & 7;
            int ss = slot ^ (row & 7);
            uint4 av = *(const uint4*)(A + (size_t)(m0 + row) * K + k0 + slot * 8);
            *(uint4*)(As + row * 64 + ss * 8) = av;
            uint4 wv = *(const uint4*)(W + (size_t)(n0 + row) * K + k0 + slot * 8);
            *(uint4*)(Bs + row * 64 + ss * 8) = wv;
        }
        __syncthreads();
#pragma unroll
        for (int kk = 0; kk < 2; ++kk) {
            short8 af[4], bf[4];
            int sl = kk * 4 + (l >> 4);
#pragma unroll
            for (int mf = 0; mf < 4; ++mf) {
                int row = wm + mf * 16 + (l & 15);
                af[mf] = *(const short8*)(As + row * 64 + (sl ^ (row & 7)) * 8);
            }
#pragma unroll
            for (int nf = 0; nf < 4; ++nf) {
                int row = wn + nf * 16 + (l & 15);
                bf[nf] = *(const short8*)(Bs + row * 64 + (sl ^ (row & 7)) * 8);
            }
#pragma unroll
            for (int mf = 0; mf < 4; ++mf)
#pragma unroll
                for (int nf = 0; nf < 4; ++nf)
                    acc[mf][nf] = __builtin_amdgcn_mfma_f32_16x16x32_bf16(
                        af[mf], bf[nf], acc[mf][nf], 0, 0, 0);
        }
    }

#pragma unroll
    for (int mf = 0; mf < 4; ++mf) {
#pragma unroll
        for (int nf = 0; nf < 4; ++nf) {
            int col = n0 + wn + nf * 16 + (l & 15);
#pragma unroll
            for (int j = 0; j < 4; ++j) {
                int row = m0 + wm + mf * 16 + (l >> 4) * 4 + j;
                float v = acc[mf][nf][j];
                if (EPI == 0) {
                    ((short*)ga.out[zi])[(size_t)row * N + col] = f2b(v);
                } else if (EPI == 1) {
                    v += ga.bias[zi][col] + ga.res[zi][(size_t)row * N + col];
                    ((float*)ga.out[zi])[(size_t)row * N + col] = v;
                } else if (EPI == 2) {
                    v = gelu_f(v + ga.bias[zi][col]);
                    ((short*)ga.out[zi])[(size_t)row * N + col] = f2b(v);
                }
            }
        }
    }
}

// ------- fused: conv reductions w/ inline gather (blocks 0..127) + local attention --
struct CLArgs {
    const short* qkv_g; const short* wk; const short* wv;
    float* kpart; float* vpart;
    const short* qkv_l; short* ob;
};
__global__ __launch_bounds__(256) void convlat_k(CLArgs ga) {
    __shared__ char smem[32768];
    int t = threadIdx.x;
    if (blockIdx.x < 128) {
        int bid = blockIdx.x;
        int m0 = (bid & 7) * 128;
        int zi = bid >> 6;
        int slice = (bid >> 3) & 7;
        const short* Abase = ga.qkv_g + (zi ? 256 : 128);
        const short* W = zi ? ga.wv : ga.wk;
        float* outp = zi ? ga.vpart : ga.kpart;
        short* As = (short*)smem;
        short* Bs = (short*)smem + 128 * 64;
        int w = t >> 6, l = t & 63;
        int wm = (w >> 1) * 64, wn = (w & 1) * 64;
        int kbeg = slice * 128;

        f32x4 acc[4][4];
#pragma unroll
        for (int a = 0; a < 4; ++a)
#pragma unroll
            for (int b = 0; b < 4; ++b) acc[a][b] = f32x4{0.f, 0.f, 0.f, 0.f};

        for (int k0 = kbeg; k0 < kbeg + 128; k0 += 64) {
            __syncthreads();
            int off = k0 >> 7;
            int od = off >> 2, oh = (off >> 1) & 1, ow = off & 1;
#pragma unroll
            for (int c = 0; c < 4; ++c) {
                int chunk = c * 256 + t;
                int row = chunk >> 3;
                int slot = chunk & 7;
                int ss = slot ^ (row & 7);
                int nr = m0 + row;
                int ci = (k0 & 127) + slot * 8;
                int n = (2 * (nr >> 8) + od) * 1024 + (2 * ((nr >> 4) & 15) + oh) * 32
                        + 2 * (nr & 15) + ow;
                uint4 av = *(const uint4*)(Abase + (size_t)n * 384 + ci);
                *(uint4*)(As + row * 64 + ss * 8) = av;
                uint4 wv2 = *(const uint4*)(W + (size_t)row * 1024 + k0 + slot * 8);
                *(uint4*)(Bs + row * 64 + ss * 8) = wv2;
            }
            __syncthreads();
#pragma unroll
            for (int kk = 0; kk < 2; ++kk) {
                short8 af[4], bf[4];
                int sl = kk * 4 + (l >> 4);
#pragma unroll
                for (int mf = 0; mf < 4; ++mf) {
                    int row = wm + mf * 16 + (l & 15);
                    af[mf] = *(const short8*)(As + row * 64 + (sl ^ (row & 7)) * 8);
                }
#pragma unroll
                for (int nf = 0; nf < 4; ++nf) {
                    int row = wn + nf * 16 + (l & 15);
                    bf[nf] = *(const short8*)(Bs + row * 64 + (sl ^ (row & 7)) * 8);
                }
#pragma unroll
                for (int mf = 0; mf < 4; ++mf)
#pragma unroll
                    for (int nf = 0; nf < 4; ++nf)
                        acc[mf][nf] = __builtin_amdgcn_mfma_f32_16x16x32_bf16(
                            af[mf], bf[nf], acc[mf][nf], 0, 0, 0);
            }
        }
#pragma unroll
        for (int mf = 0; mf < 4; ++mf)
#pragma unroll
            for (int nf = 0; nf < 4; ++nf) {
                int col = wn + nf * 16 + (l & 15);
#pragma unroll
                for (int j = 0; j < 4; ++j) {
                    int row = m0 + wm + mf * 16 + (l >> 4) * 4 + j;
                    outp[(size_t)slice * (NR * C_DIM) + (size_t)row * C_DIM + col] =
                        acc[mf][nf][j];
                }
            }
        return;
    }
    float (*ks)[32][HDIM] = (float(*)[32][HDIM])smem;
    float (*vs)[32][HDIM] = (float(*)[32][HDIM])(smem + 16384);
    int m = t & 31, h = t >> 5, r = blockIdx.x - 128;
    int zd = r >> 6, zh = (r >> 3) & 7, zw = r & 7;
    int pd = m >> 4, ph = (m >> 2) & 3, pw = m & 3;
    int n = (zd * 2 + pd) * 1024 + (zh * 4 + ph) * 32 + (zw * 4 + pw);
    const short* base = ga.qkv_l + (size_t)n * 384 + h * HDIM;
    float q[16], kt[16], vt[16];
    ld16bf(base, q);
    ld16bf(base + 128, kt);
    ld16bf(base + 256, vt);
#pragma unroll
    for (int d = 0; d < 16; ++d) { ks[h][m][d] = kt[d]; vs[h][m][d] = vt[d]; }
    __syncthreads();
    float s[32];
#pragma unroll
    for (int j = 0; j < 32; ++j) {
        float d = 0.f;
#pragma unroll
        for (int dd = 0; dd < 16; ++dd) d += q[dd] * ks[h][j][dd];
        s[j] = __expf(d * QK_SCALE);
    }
    float sum = 0.f;
#pragma unroll
    for (int j = 0; j < 32; ++j) sum += s[j];
    float inv = 1.0f / sum;
    float oo[16] = {};
#pragma unroll
    for (int j = 0; j < 32; ++j) {
        float p = s[j] * inv;
#pragma unroll
        for (int dd = 0; dd < 16; ++dd) oo[dd] += p * vs[h][j][dd];
    }
#pragma unroll
    for (int dd = 0; dd < 16; ++dd) {
        int n2 = h * 4 + (dd >> 2);
        int c2 = (dd & 3) * 32 + m;
        int pd2 = n2 >> 4, ph2 = (n2 >> 2) & 3, pw2 = n2 & 3;
        int nn = (zd * 2 + pd2) * 1024 + (zh * 4 + ph2) * 32 + (zw * 4 + pw2);
        ga.ob[(size_t)nn * C_DIM + c2] = f2b(oo[dd]);
    }
}

// ------- sum 8 split-K partials + per-head LN; K -> bf16 *0.25*log2e, V -> bf16^T ---
__global__ __launch_bounds__(256) void ln_head_sum_k(const float* __restrict__ kpart,
                                                     const float* __restrict__ vpart,
                                                     const float* __restrict__ gk, const float* __restrict__ bk,
                                                     const float* __restrict__ gv, const float* __restrict__ bv,
                                                     short* __restrict__ kout, short* __restrict__ vout) {
    int idx = blockIdx.x * 256 + threadIdx.x;   // 0..16383
    bool sel = idx >= 8192;
    int id2 = idx & 8191;
    const float* part = sel ? vpart : kpart;
    const float* g    = sel ? gv : gk;
    const float* b    = sel ? bv : bk;
    int nr = id2 >> 3, h = id2 & 7;
    size_t base = (size_t)nr * C_DIM + h * HDIM;
    float v[16] = {};
#pragma unroll
    for (int p = 0; p < 8; ++p) {
        const float* pp = part + (size_t)p * (NR * C_DIM) + base;
#pragma unroll
        for (int d4 = 0; d4 < 4; ++d4) {
            float4 t = *(const float4*)(pp + d4 * 4);
            v[d4 * 4 + 0] += t.x; v[d4 * 4 + 1] += t.y;
            v[d4 * 4 + 2] += t.z; v[d4 * 4 + 3] += t.w;
        }
    }
    float s = 0.f;
#pragma unroll
    for (int i = 0; i < 16; ++i) s += v[i];
    float m = s * (1.0f / 16.0f);
    float sq = 0.f;
#pragma unroll
    for (int i = 0; i < 16; ++i) { float d = v[i] - m; sq += d * d; }
    float rs = rsqrtf(sq * (1.0f / 16.0f) + EPSV);
    if (!sel) {
        short* op = kout + (size_t)h * (NR * HDIM) + (size_t)nr * HDIM;
#pragma unroll
        for (int i = 0; i < 16; ++i)
            op[i] = f2b(((v[i] - m) * rs * g[i] + b[i]) * QK_L2E);
    } else {
        short* op = vout + (size_t)h * (HDIM * NR) + nr;
#pragma unroll
        for (int i = 0; i < 16; ++i)
            op[(size_t)i * NR] = f2b((v[i] - m) * rs * g[i] + b[i]);
    }
}

// ---------------- global attention v8: 8 waves, split-K wave pairs ----------------
// grid (128, 8); block 512. wave w: q-tile (w&3), key-half (w>>2) of 512 keys.
__global__ __launch_bounds__(512) void gattn_k(const short* __restrict__ qkv,
                                               const short* __restrict__ kb,   // [8][1024][16] *0.25*log2e
                                               const short* __restrict__ vt,   // [8][16][1024]
                                               short* __restrict__ ob) {
    __shared__ short plds[8][2048];
    __shared__ float comb[4][64][5];
    int t = threadIdx.x;
    int w = t >> 6, l = t & 63;
    int h = blockIdx.y;
    int lr = l & 15, lq = l >> 4;
    int qw = w & 3, kw = w >> 2;
    int q0 = blockIdx.x * 64 + qw * 16;

    short8 qf = short8{0, 0, 0, 0, 0, 0, 0, 0};
    if (lq < 2)
        qf = *(const short8*)(qkv + (size_t)(q0 + lr) * 384 + h * HDIM + lq * 8);

    const short* kh = kb + (size_t)h * (NR * HDIM);
    const short* vh = vt + (size_t)h * (HDIM * NR);
    short* pw = &plds[w][0];

    const f32x4 zz = {0.f, 0.f, 0.f, 0.f};
    f32x4 oacc = {0.f, 0.f, 0.f, 0.f};
    float rs = 0.f;

    for (int c = 0; c < 4; ++c) {
        int kbase = kw * 512 + c * 128;
        f32x4 s[8];
#pragma unroll
        for (int nf = 0; nf < 8; ++nf) {
            short8 kf = short8{0, 0, 0, 0, 0, 0, 0, 0};
            if (lq < 2)
                kf = *(const short8*)(kh + (size_t)(kbase + nf * 16 + lr) * HDIM + lq * 8);
            s[nf] = __builtin_amdgcn_mfma_f32_16x16x32_bf16(kf, qf, zz, 0, 0, 0);
        }
#pragma unroll
        for (int nf = 0; nf < 8; ++nf) {
            float p0 = exp2f(s[nf][0]);
            float p1 = exp2f(s[nf][1]);
            float p2 = exp2f(s[nf][2]);
            float p3 = exp2f(s[nf][3]);
            rs += (p0 + p1) + (p2 + p3);
            unsigned int u01, u23;
            asm("v_cvt_pk_bf16_f32 %0, %1, %2" : "=v"(u01) : "v"(p0), "v"(p1));
            asm("v_cvt_pk_bf16_f32 %0, %1, %2" : "=v"(u23) : "v"(p2), "v"(p3));
            int k0 = nf * 16 + lq * 4;
            int sw = (lr & 7) << 3;
            *(unsigned int*)&pw[lr * 128 + (k0 ^ sw)]       = u01;
            *(unsigned int*)&pw[lr * 128 + ((k0 + 2) ^ sw)] = u23;
        }
#pragma unroll
        for (int ks = 0; ks < 4; ++ks) {
            short8 pf = *(const short8*)&pw[(lr * 128 + ks * 32 + lq * 8) ^ ((lr & 7) << 3)];
            short8 vf = *(const short8*)(vh + (size_t)lr * NR + kbase + ks * 32 + lq * 8);
            oacc = __builtin_amdgcn_mfma_f32_16x16x32_bf16(pf, vf, oacc, 0, 0, 0);
        }
    }
    rs += __shfl_xor(rs, 16);
    rs += __shfl_xor(rs, 32);
    if (w >= 4) {
        comb[w - 4][l][0] = oacc[0];
        comb[w - 4][l][1] = oacc[1];
        comb[w - 4][l][2] = oacc[2];
        comb[w - 4][l][3] = oacc[3];
        comb[w - 4][l][4] = rs;
    }
    __syncthreads();
    if (w < 4) {
        oacc[0] += comb[w][l][0];
        oacc[1] += comb[w][l][1];
        oacc[2] += comb[w][l][2];
        oacc[3] += comb[w][l][3];
        rs += comb[w][l][4];
        float r0 = __shfl(rs, lq * 4 + 0);
        float r1 = __shfl(rs, lq * 4 + 1);
        float r2 = __shfl(rs, lq * 4 + 2);
        float r3 = __shfl(rs, lq * 4 + 3);
        size_t base_o = (size_t)(q0 + lq * 4) * C_DIM + h * HDIM + lr;
        ob[base_o]             = f2b(oacc[0] / r0);
        ob[base_o + C_DIM]     = f2b(oacc[1] / r1);
        ob[base_o + 2 * C_DIM] = f2b(oacc[2] / r2);
        ob[base_o + 3 * C_DIM] = f2b(oacc[3] / r3);
    }
}

// ---------------- final gate: out(C,N) = x * sigmoid(loc + glo) ----------------
__global__ __launch_bounds__(256) void gate_k(const float* __restrict__ x,
                                              const float* __restrict__ lf, const float* __restrict__ gf,
                                              float* __restrict__ out) {
    __shared__ float tile[32][33];
    int n0 = blockIdx.x * 32, c0 = blockIdx.y * 32;
    int tx = threadIdx.x, ty = threadIdx.y;
#pragma unroll
    for (int k = 0; k < 4; ++k) {
        int n = n0 + ty + k * 8, c = c0 + tx;
        tile[ty + k * 8][tx] = lf[(size_t)n * C_DIM + c] + gf[(size_t)n * C_DIM + c];
    }
    __syncthreads();
#pragma unroll
    for (int k = 0; k < 4; ++k) {
        int c = c0 + ty + k * 8, n = n0 + tx;
        float z = tile[tx][ty + k * 8];
        float sg = 1.0f / (1.0f + __expf(-z));
        out[(size_t)c * N_TOK + n] = x[(size_t)c * N_TOK + n] * sg;
    }
}

extern "C" void kernel_launch(void* const* d_in, const int* in_sizes, int n_in,
                              void* d_out, int out_size, void* d_ws, size_t ws_size,
                              hipStream_t stream) {
    const float* x        = (const float*)d_in[0];
    const float* l_n1_g   = (const float*)d_in[1];
    const float* l_n1_b   = (const float*)d_in[2];
    const float* l_qkv_w  = (const float*)d_in[3];
    const float* l_proj_w = (const float*)d_in[4];
    const float* l_proj_b = (const float*)d_in[5];
    const float* l_n2_g   = (const float*)d_in[6];
    const float* l_n2_b   = (const float*)d_in[7];
    const float* l_fc1_w  = (const float*)d_in[8];
    const float* l_fc1_b  = (const float*)d_in[9];
    const float* l_fc2_w  = (const float*)d_in[10];
    const float* l_fc2_b  = (const float*)d_in[11];
    const float* g_n1_g   = (const float*)d_in[12];
    const float* g_n1_b   = (const float*)d_in[13];
    const float* g_qkv_w  = (const float*)d_in[14];
    const float* g_proj_w = (const float*)d_in[15];
    const float* g_proj_b = (const float*)d_in[16];
    const float* g_n2_g   = (const float*)d_in[17];
    const float* g_n2_b   = (const float*)d_in[18];
    const float* g_fc1_w  = (const float*)d_in[19];
    const float* g_fc1_b  = (const float*)d_in[20];
    const float* g_fc2_w  = (const float*)d_in[21];
    const float* g_fc2_b  = (const float*)d_in[22];
    const float* g_ke_w   = (const float*)d_in[23];
    const float* g_ve_w   = (const float*)d_in[24];
    const float* g_nk_g   = (const float*)d_in[25];
    const float* g_nk_b   = (const float*)d_in[26];
    const float* g_nv_g   = (const float*)d_in[27];
    const float* g_nv_b   = (const float*)d_in[28];
    float* out = (float*)d_out;

    char* base = (char*)d_ws;
    float* xt     = (float*)(base);                        // 0-4 MB
    float* t1_l   = (float*)(base + (4ull  << 20));        // 4-8 MB
    float* t1_g   = (float*)(base + (8ull  << 20));        // 8-12 MB
    short* yA16   = (short*)(base + (12ull << 20));        // 12-14 (later t2_l)
    short* yG16   = (short*)(base + (14ull << 20));        // 14-16 (later t2_g)
    short* t2_l   = yA16;
    short* t2_g   = yG16;
    float* locfin = (float*)(base + (12ull << 20));        // 12-16 (after fc1 reads t2)
    short* obuf_l = (short*)(base + (16ull << 20));        // 16-18
    short* obuf_g = (short*)(base + (18ull << 20));        // 18-20
    float* glofin = (float*)(base + (16ull << 20));        // 16-20 (after proj reads obuf)
    short* qkv_l  = (short*)(base + (20ull << 20));        // 20-26
    short* qkv_g  = (short*)(base + (26ull << 20));        // 26-32
    short* h1_l   = (short*)(base + (32ull << 20));        // 32-40 (after ln_head)
    float* kpart  = (float*)(base + (32ull << 20));        // 32-36 (pre-fc1)
    float* vpart  = (float*)(base + (36ull << 20));        // 36-40 (pre-fc1)
    short* h1_g   = (short*)(base + (40ull << 20));        // 40-48
    short* kb16   = (short*)(base + (48ull << 20));        // [8][1024][16]
    short* vt16   = (short*)(base + (48ull << 20) + (512ull << 10)); // [8][16][1024]
    short* wts    = (short*)(base + (49ull << 20));        // ~1.3 MB

    const int L_QKV = 0,      L_PROJ = 49152, L_FC1 = 65536,  L_FC2 = 131072;
    const int G_QKV = 196608, G_PROJ = 245760, G_FC1 = 262144, G_FC2 = 327680;
    const int G_KE  = 393216, G_VE   = 524288;

    CvtArgs ca;
    ca.d[0] = {l_qkv_w,  wts + L_QKV,  49152, 0};
    ca.d[1] = {l_proj_w, wts + L_PROJ, 16384, 0};
    ca.d[2] = {l_fc1_w,  wts + L_FC1,  65536, 0};
    ca.d[3] = {l_fc2_w,  wts + L_FC2,  65536, 0};
    ca.d[4] = {g_qkv_w,  wts + G_QKV,  49152, 0};
    ca.d[5] = {g_proj_w, wts + G_PROJ, 16384, 0};
    ca.d[6] = {g_fc1_w,  wts + G_FC1,  65536, 0};
    ca.d[7] = {g_fc2_w,  wts + G_FC2,  65536, 0};
    ca.d[8] = {g_ke_w,   wts + G_KE,  131072, 1};   // permuted: [co][off*128+ci]
    ca.d[9] = {g_ve_w,   wts + G_VE,  131072, 1};

    // 1: transpose + LN1 + weight cvt (fused)
    prep_k<<<296, 256, 0, stream>>>(x, l_n1_g, l_n1_b, g_n1_g, g_n1_b, xt, yA16, yG16, ca);

    // 2: both qkv GEMMs
    MArgs a_qkv = {{yA16, yG16}, {wts + L_QKV, wts + G_QKV}, {nullptr, nullptr}, {nullptr, nullptr}, {qkv_l, qkv_g}};
    mgemm_k<0><<<dim3(64, 3, 2), 256, 0, stream>>>(a_qkv, N_TOK, 384, 128);

    // 3: conv reductions (inline gather, split-K x8) + local attention (fused)
    CLArgs cla = {qkv_g, wts + G_KE, wts + G_VE, kpart, vpart, qkv_l, obuf_l};
    convlat_k<<<384, 256, 0, stream>>>(cla);

    // 4: head-LN for K (scaled for exp2) and V^T
    ln_head_sum_k<<<64, 256, 0, stream>>>(kpart, vpart, g_nk_g, g_nk_b, g_nv_g, g_nv_b, kb16, vt16);

    // 5: global attention (MFMA flash v8, split-K wave pairs)
    gattn_k<<<dim3(128, 8), 512, 0, stream>>>(qkv_g, kb16, vt16, obuf_g);

    // 6: both proj GEMMs (+bias+residual)
    MArgs a_pj = {{obuf_l, obuf_g}, {wts + L_PROJ, wts + G_PROJ}, {l_proj_b, g_proj_b}, {xt, xt}, {t1_l, t1_g}};
    mgemm_k<1><<<dim3(64, 1, 2), 256, 0, stream>>>(a_pj, N_TOK, 128, 128);

    // 7: both second LNs
    ln2_pair_k<<<4096, 256, 0, stream>>>(t1_l, l_n2_g, l_n2_b, t2_l, t1_g, g_n2_g, g_n2_b, t2_g);

    // 8: both fc1 GEMMs (+bias+gelu)
    MArgs a_f1 = {{t2_l, t2_g}, {wts + L_FC1, wts + G_FC1}, {l_fc1_b, g_fc1_b}, {nullptr, nullptr}, {h1_l, h1_g}};
    mgemm_k<2><<<dim3(64, 4, 2), 256, 0, stream>>>(a_f1, N_TOK, 512, 128);

    // 9: both fc2 GEMMs (+bias+residual)
    MArgs a_f2 = {{h1_l, h1_g}, {wts + L_FC2, wts + G_FC2}, {l_fc2_b, g_fc2_b}, {t1_l, t1_g}, {locfin, glofin}};
    mgemm_k<1><<<dim3(64, 1, 2), 256, 0, stream>>>(a_f2, N_TOK, 128, 512);

    // 10: gate
    gate_k<<<dim3(256, 4), dim3(32, 8), 0, stream>>>(x, locfin, glofin, out);
}

// Round 11
// 137.973 us; speedup vs baseline: 1.1369x; 1.0200x over previous
//
#include <hip/hip_runtime.h>
#include <math.h>

#define N_TOK 8192
#define C_DIM 128
#define NHD   8
#define HDIM  16
#define NR    1024
#define EPSV  1e-5f
#define QK_SCALE 0.25f
#define QK_L2E  0.36067376f   /* 0.25 * log2(e) */

typedef __attribute__((ext_vector_type(8))) short short8;
typedef __attribute__((ext_vector_type(4))) float f32x4;

__device__ __forceinline__ float gelu_f(float v) {
    // tanh-form gelu: 0.5v(1+tanh(u)) = v*sigmoid(2u); |err vs erf-gelu| < ~1e-3
    float u = 0.7978845608f * (v + 0.044715f * v * v * v);
    float e = exp2f(2.885390082f * u);
    return v * (e / (e + 1.0f));
}
__device__ __forceinline__ float uaf(unsigned int u) {
    union { unsigned int u; float f; } x; x.u = u; return x.f;
}
__device__ __forceinline__ short f2b(float v) {
    union { float f; unsigned int u; } x; x.f = v;
    unsigned int r = x.u + 0x7fffu + ((x.u >> 16) & 1u);
    return (short)(r >> 16);
}
__device__ __forceinline__ unsigned int pk2(float a, float b) {
    return (unsigned int)(unsigned short)f2b(a) | ((unsigned int)(unsigned short)f2b(b) << 16);
}
__device__ __forceinline__ void ld16bf(const short* p, float* d) {
    uint4 a = *(const uint4*)p;
    uint4 b = *(const uint4*)(p + 8);
    d[0]  = uaf(a.x << 16); d[1]  = uaf(a.x & 0xffff0000u);
    d[2]  = uaf(a.y << 16); d[3]  = uaf(a.y & 0xffff0000u);
    d[4]  = uaf(a.z << 16); d[5]  = uaf(a.z & 0xffff0000u);
    d[6]  = uaf(a.w << 16); d[7]  = uaf(a.w & 0xffff0000u);
    d[8]  = uaf(b.x << 16); d[9]  = uaf(b.x & 0xffff0000u);
    d[10] = uaf(b.y << 16); d[11] = uaf(b.y & 0xffff0000u);
    d[12] = uaf(b.z << 16); d[13] = uaf(b.z & 0xffff0000u);
    d[14] = uaf(b.w << 16); d[15] = uaf(b.w & 0xffff0000u);
}

// async global->LDS, 16B per lane; LDS dest = wave-uniform base + lane*16
__device__ __forceinline__ void gload16(const void* g, void* l) {
    __builtin_amdgcn_global_load_lds(
        (const __attribute__((address_space(1))) unsigned int*)g,
        (__attribute__((address_space(3))) unsigned int*)l, 16, 0, 0);
}

struct CvtDesc { const float* src; short* dst; int n; int pad; };
struct CvtArgs { CvtDesc d[10]; };

// ------- fused: transpose+LN1 (blocks 0..255) + weight cvt (blocks 256..295) --------
__global__ __launch_bounds__(256) void prep_k(const float* __restrict__ x,
                                              const float* __restrict__ g1, const float* __restrict__ b1,
                                              const float* __restrict__ g2, const float* __restrict__ b2,
                                              float* __restrict__ xt,
                                              short* __restrict__ o1, short* __restrict__ o2,
                                              CvtArgs ca) {
    __shared__ float tile[32][132];
    int t = threadIdx.x;
    if (blockIdx.x >= 256) {
        int bid = blockIdx.x - 256;   // 0..39
#pragma unroll 1
        for (int d = 0; d < 10; ++d) {
            CvtDesc dd = ca.d[d];
            if (dd.pad) {
                for (int i = bid * 256 + t; i < dd.n; i += 40 * 256) {
                    int co = i >> 10, qq = i & 1023;
                    dd.dst[co * 1024 + ((qq & 7) << 7) + (qq >> 3)] = f2b(dd.src[i]);
                }
            } else {
                for (int i = bid * 256 + t; i < dd.n; i += 40 * 256)
                    dd.dst[i] = f2b(dd.src[i]);
            }
        }
        return;
    }
    int n0 = blockIdx.x * 32;
#pragma unroll
    for (int k = 0; k < 16; ++k) {
        int f = t + k * 256;
        int n = f & 31, c = f >> 5;
        tile[n][c] = x[(size_t)c * N_TOK + n0 + n];
    }
    __syncthreads();
    int tk = t >> 3, cb = (t & 7) * 16;
    float v[16];
    float s = 0.f, sq = 0.f;
#pragma unroll
    for (int i = 0; i < 16; ++i) {
        v[i] = tile[tk][cb + i];
        s += v[i]; sq += v[i] * v[i];
    }
    s += __shfl_xor(s, 1);  s += __shfl_xor(s, 2);  s += __shfl_xor(s, 4);
    sq += __shfl_xor(sq, 1); sq += __shfl_xor(sq, 2); sq += __shfl_xor(sq, 4);
    float m = s * (1.0f / 128.0f);
    float var = sq * (1.0f / 128.0f) - m * m;
    float rs = rsqrtf(var + EPSV);
    int tok = n0 + tk;
    float* xp = xt + (size_t)tok * C_DIM + cb;
    *(float4*)(xp)      = make_float4(v[0], v[1], v[2], v[3]);
    *(float4*)(xp + 4)  = make_float4(v[4], v[5], v[6], v[7]);
    *(float4*)(xp + 8)  = make_float4(v[8], v[9], v[10], v[11]);
    *(float4*)(xp + 12) = make_float4(v[12], v[13], v[14], v[15]);
    float hA[16], hB[16];
#pragma unroll
    for (int i = 0; i < 16; ++i) {
        float hn = (v[i] - m) * rs;
        hA[i] = hn * g1[cb + i] + b1[cb + i];
        hB[i] = hn * g2[cb + i] + b2[cb + i];
    }
    uint4 ua0 = {pk2(hA[0], hA[1]), pk2(hA[2], hA[3]), pk2(hA[4], hA[5]), pk2(hA[6], hA[7])};
    uint4 ua1 = {pk2(hA[8], hA[9]), pk2(hA[10], hA[11]), pk2(hA[12], hA[13]), pk2(hA[14], hA[15])};
    uint4 ub0 = {pk2(hB[0], hB[1]), pk2(hB[2], hB[3]), pk2(hB[4], hB[5]), pk2(hB[6], hB[7])};
    uint4 ub1 = {pk2(hB[8], hB[9]), pk2(hB[10], hB[11]), pk2(hB[12], hB[13]), pk2(hB[14], hB[15])};
    *(uint4*)(o1 + (size_t)tok * C_DIM + cb)     = ua0;
    *(uint4*)(o1 + (size_t)tok * C_DIM + cb + 8) = ua1;
    *(uint4*)(o2 + (size_t)tok * C_DIM + cb)     = ub0;
    *(uint4*)(o2 + (size_t)tok * C_DIM + cb + 8) = ub1;
}

// ---------------- second LN, paired across branches ----------------
__global__ __launch_bounds__(256) void ln2_pair_k(const float* __restrict__ in0,
                                                  const float* __restrict__ g0, const float* __restrict__ b0,
                                                  short* __restrict__ o0,
                                                  const float* __restrict__ in1,
                                                  const float* __restrict__ g1, const float* __restrict__ b1,
                                                  short* __restrict__ o1) {
    int blk = blockIdx.x;
    bool sel = blk >= 2048;
    blk &= 2047;
    const float* in = sel ? in1 : in0;
    const float* g  = sel ? g1 : g0;
    const float* b  = sel ? b1 : b0;
    short* o        = sel ? o1 : o0;
    int lane = threadIdx.x & 63;
    int n = blk * 4 + (threadIdx.x >> 6);
    float v0 = in[(size_t)n * C_DIM + lane];
    float v1 = in[(size_t)n * C_DIM + 64 + lane];
    float s = v0 + v1, sq = v0 * v0 + v1 * v1;
#pragma unroll
    for (int off = 32; off >= 1; off >>= 1) {
        s += __shfl_xor(s, off);
        sq += __shfl_xor(sq, off);
    }
    float m = s * (1.0f / 128.0f);
    float var = sq * (1.0f / 128.0f) - m * m;
    float rs = rsqrtf(var + EPSV);
    o[(size_t)n * C_DIM + lane]      = f2b((v0 - m) * rs * g[lane] + b[lane]);
    o[(size_t)n * C_DIM + 64 + lane] = f2b((v1 - m) * rs * g[lane + 64] + b[lane + 64]);
}

// ---------------- bf16 MFMA GEMM, async-staged 2-phase pipeline ----------------
// EPI: 0 bf16 out; 1 f32 = acc+bias+res; 2 bf16 = gelu(acc+bias)
struct MArgs {
    const short* A[2]; const short* W[2];
    const float* bias[2]; const float* res[2];
    void* out[2];
};
template <int EPI>
__global__ __launch_bounds__(256) void mgemm_k(MArgs ga, int M, int N, int K) {
    int zi = blockIdx.z;
    const short* A = ga.A[zi];
    const short* W = ga.W[zi];
    __shared__ short As[2][128 * 64];
    __shared__ short Bs[2][128 * 64];
    int t = threadIdx.x;
    int w = t >> 6, l = t & 63;
    int m0 = blockIdx.x * 128, n0 = blockIdx.y * 128;
    int wm = (w >> 1) * 64, wn = (w & 1) * 64;

    f32x4 acc[4][4];
#pragma unroll
    for (int a = 0; a < 4; ++a)
#pragma unroll
        for (int b = 0; b < 4; ++b) acc[a][b] = f32x4{0.f, 0.f, 0.f, 0.f};

    // pre-swizzled-source staging: LDS linear per wave, global addr carries the XOR
    auto STAGE = [&](int buf, int k0) {
#pragma unroll
        for (int c = 0; c < 4; ++c) {
            int g0 = c * 256 + w * 64;
            int g  = g0 + l;
            int row = g >> 3, ss = g & 7;
            int slot = ss ^ (row & 7);
            gload16(A + (size_t)(m0 + row) * K + k0 + slot * 8, &As[buf][g0 * 8]);
            gload16(W + (size_t)(n0 + row) * K + k0 + slot * 8, &Bs[buf][g0 * 8]);
        }
    };

    int NT = K >> 6;
    STAGE(0, 0);
    int cur = 0;
    for (int it = 0; it < NT; ++it) {
        if (it + 1 < NT) {
            STAGE(cur ^ 1, (it + 1) << 6);
            asm volatile("s_waitcnt vmcnt(8)" ::: "memory");   // current tile landed
        } else {
            asm volatile("s_waitcnt vmcnt(0)" ::: "memory");
        }
        __builtin_amdgcn_s_barrier();
#pragma unroll
        for (int kk = 0; kk < 2; ++kk) {
            short8 af[4], bf[4];
            int sl = kk * 4 + (l >> 4);
#pragma unroll
            for (int mf = 0; mf < 4; ++mf) {
                int row = wm + mf * 16 + (l & 15);
                af[mf] = *(const short8*)(&As[cur][row * 64 + (sl ^ (row & 7)) * 8]);
            }
#pragma unroll
            for (int nf = 0; nf < 4; ++nf) {
                int row = wn + nf * 16 + (l & 15);
                bf[nf] = *(const short8*)(&Bs[cur][row * 64 + (sl ^ (row & 7)) * 8]);
            }
#pragma unroll
            for (int mf = 0; mf < 4; ++mf)
#pragma unroll
                for (int nf = 0; nf < 4; ++nf)
                    acc[mf][nf] = __builtin_amdgcn_mfma_f32_16x16x32_bf16(
                        af[mf], bf[nf], acc[mf][nf], 0, 0, 0);
        }
        asm volatile("s_waitcnt lgkmcnt(0)" ::: "memory");
        __builtin_amdgcn_sched_barrier(0);
        __builtin_amdgcn_s_barrier();
        cur ^= 1;
    }

    // C/D layout: col = lane&15, row = (lane>>4)*4 + reg
#pragma unroll
    for (int mf = 0; mf < 4; ++mf) {
#pragma unroll
        for (int nf = 0; nf < 4; ++nf) {
            int col = n0 + wn + nf * 16 + (l & 15);
#pragma unroll
            for (int j = 0; j < 4; ++j) {
                int row = m0 + wm + mf * 16 + (l >> 4) * 4 + j;
                float v = acc[mf][nf][j];
                if (EPI == 0) {
                    ((short*)ga.out[zi])[(size_t)row * N + col] = f2b(v);
                } else if (EPI == 1) {
                    v += ga.bias[zi][col] + ga.res[zi][(size_t)row * N + col];
                    ((float*)ga.out[zi])[(size_t)row * N + col] = v;
                } else if (EPI == 2) {
                    v = gelu_f(v + ga.bias[zi][col]);
                    ((short*)ga.out[zi])[(size_t)row * N + col] = f2b(v);
                }
            }
        }
    }
}

// ------- fused: conv reductions w/ inline gather (blocks 0..127) + local attention --
struct CLArgs {
    const short* qkv_g; const short* wk; const short* wv;
    float* kpart; float* vpart;
    const short* qkv_l; short* ob;
};
__global__ __launch_bounds__(256) void convlat_k(CLArgs ga) {
    __shared__ char smem[65536];
    int t = threadIdx.x;
    if (blockIdx.x < 128) {
        int bid = blockIdx.x;
        int m0 = (bid & 7) * 128;
        int zi = bid >> 6;
        int slice = (bid >> 3) & 7;
        const short* Abase = ga.qkv_g + (zi ? 256 : 128);
        const short* W = zi ? ga.wv : ga.wk;
        float* outp = zi ? ga.vpart : ga.kpart;
        short (*As)[8192] = (short(*)[8192])smem;
        short (*Bs)[8192] = (short(*)[8192])(smem + 32768);
        int w = t >> 6, l = t & 63;
        int wm = (w >> 1) * 64, wn = (w & 1) * 64;
        int kbeg = slice * 128;
        int od = slice >> 2, oh = (slice >> 1) & 1, ow = slice & 1;

        f32x4 acc[4][4];
#pragma unroll
        for (int a = 0; a < 4; ++a)
#pragma unroll
            for (int b = 0; b < 4; ++b) acc[a][b] = f32x4{0.f, 0.f, 0.f, 0.f};

        auto STAGE = [&](int buf, int k0) {
#pragma unroll
            for (int c = 0; c < 4; ++c) {
                int g0 = c * 256 + w * 64;
                int g  = g0 + l;
                int row = g >> 3, ss = g & 7;
                int slot = ss ^ (row & 7);
                int nr = m0 + row;
                int n = (2 * (nr >> 8) + od) * 1024 + (2 * ((nr >> 4) & 15) + oh) * 32
                        + 2 * (nr & 15) + ow;
                gload16(Abase + (size_t)n * 384 + (k0 & 127) + slot * 8, &As[buf][g0 * 8]);
                gload16(W + (size_t)row * 1024 + k0 + slot * 8, &Bs[buf][g0 * 8]);
            }
        };

        STAGE(0, kbeg);
        int cur = 0;
        for (int it = 0; it < 2; ++it) {
            if (it == 0) {
                STAGE(1, kbeg + 64);
                asm volatile("s_waitcnt vmcnt(8)" ::: "memory");
            } else {
                asm volatile("s_waitcnt vmcnt(0)" ::: "memory");
            }
            __builtin_amdgcn_s_barrier();
#pragma unroll
            for (int kk = 0; kk < 2; ++kk) {
                short8 af[4], bf[4];
                int sl = kk * 4 + (l >> 4);
#pragma unroll
                for (int mf = 0; mf < 4; ++mf) {
                    int row = wm + mf * 16 + (l & 15);
                    af[mf] = *(const short8*)(&As[cur][row * 64 + (sl ^ (row & 7)) * 8]);
                }
#pragma unroll
                for (int nf = 0; nf < 4; ++nf) {
                    int row = wn + nf * 16 + (l & 15);
                    bf[nf] = *(const short8*)(&Bs[cur][row * 64 + (sl ^ (row & 7)) * 8]);
                }
#pragma unroll
                for (int mf = 0; mf < 4; ++mf)
#pragma unroll
                    for (int nf = 0; nf < 4; ++nf)
                        acc[mf][nf] = __builtin_amdgcn_mfma_f32_16x16x32_bf16(
                            af[mf], bf[nf], acc[mf][nf], 0, 0, 0);
            }
            asm volatile("s_waitcnt lgkmcnt(0)" ::: "memory");
            __builtin_amdgcn_sched_barrier(0);
            __builtin_amdgcn_s_barrier();
            cur ^= 1;
        }
#pragma unroll
        for (int mf = 0; mf < 4; ++mf)
#pragma unroll
            for (int nf = 0; nf < 4; ++nf) {
                int col = wn + nf * 16 + (l & 15);
#pragma unroll
                for (int j = 0; j < 4; ++j) {
                    int row = m0 + wm + mf * 16 + (l >> 4) * 4 + j;
                    outp[(size_t)slice * (NR * C_DIM) + (size_t)row * C_DIM + col] =
                        acc[mf][nf][j];
                }
            }
        return;
    }
    float (*ks)[32][HDIM] = (float(*)[32][HDIM])smem;
    float (*vs)[32][HDIM] = (float(*)[32][HDIM])(smem + 16384);
    int m = t & 31, h = t >> 5, r = blockIdx.x - 128;
    int zd = r >> 6, zh = (r >> 3) & 7, zw = r & 7;
    int pd = m >> 4, ph = (m >> 2) & 3, pw = m & 3;
    int n = (zd * 2 + pd) * 1024 + (zh * 4 + ph) * 32 + (zw * 4 + pw);
    const short* base = ga.qkv_l + (size_t)n * 384 + h * HDIM;
    float q[16], kt[16], vt[16];
    ld16bf(base, q);
    ld16bf(base + 128, kt);
    ld16bf(base + 256, vt);
#pragma unroll
    for (int d = 0; d < 16; ++d) { ks[h][m][d] = kt[d]; vs[h][m][d] = vt[d]; }
    __syncthreads();
    float s[32];
#pragma unroll
    for (int j = 0; j < 32; ++j) {
        float d = 0.f;
#pragma unroll
        for (int dd = 0; dd < 16; ++dd) d += q[dd] * ks[h][j][dd];
        s[j] = __expf(d * QK_SCALE);
    }
    float sum = 0.f;
#pragma unroll
    for (int j = 0; j < 32; ++j) sum += s[j];
    float inv = 1.0f / sum;
    float oo[16] = {};
#pragma unroll
    for (int j = 0; j < 32; ++j) {
        float p = s[j] * inv;
#pragma unroll
        for (int dd = 0; dd < 16; ++dd) oo[dd] += p * vs[h][j][dd];
    }
#pragma unroll
    for (int dd = 0; dd < 16; ++dd) {
        int n2 = h * 4 + (dd >> 2);
        int c2 = (dd & 3) * 32 + m;
        int pd2 = n2 >> 4, ph2 = (n2 >> 2) & 3, pw2 = n2 & 3;
        int nn = (zd * 2 + pd2) * 1024 + (zh * 4 + ph2) * 32 + (zw * 4 + pw2);
        ga.ob[(size_t)nn * C_DIM + c2] = f2b(oo[dd]);
    }
}

// ------- sum 8 split-K partials + per-head LN; K -> bf16 *0.25*log2e, V -> bf16^T ---
// blocks 0..31: K (direct contiguous stores). blocks 32..63: V (LDS-transposed stores).
__global__ __launch_bounds__(256) void ln_head_sum_k(const float* __restrict__ kpart,
                                                     const float* __restrict__ vpart,
                                                     const float* __restrict__ gk, const float* __restrict__ bk,
                                                     const float* __restrict__ gv, const float* __restrict__ bv,
                                                     short* __restrict__ kout, short* __restrict__ vout) {
    __shared__ float vlds[8][16][33];
    int t = threadIdx.x;
    bool sel = blockIdx.x >= 32;
    int b = sel ? (blockIdx.x - 32) : blockIdx.x;
    int id2 = b * 256 + t;
    const float* part = sel ? vpart : kpart;
    const float* g    = sel ? gv : gk;
    const float* bb   = sel ? bv : bk;
    int nr = id2 >> 3, h = id2 & 7;
    size_t base = (size_t)nr * C_DIM + h * HDIM;
    float v[16] = {};
#pragma unroll
    for (int p = 0; p < 8; ++p) {
        const float* pp = part + (size_t)p * (NR * C_DIM) + base;
#pragma unroll
        for (int d4 = 0; d4 < 4; ++d4) {
            float4 tv = *(const float4*)(pp + d4 * 4);
            v[d4 * 4 + 0] += tv.x; v[d4 * 4 + 1] += tv.y;
            v[d4 * 4 + 2] += tv.z; v[d4 * 4 + 3] += tv.w;
        }
    }
    float s = 0.f;
#pragma unroll
    for (int i = 0; i < 16; ++i) s += v[i];
    float m = s * (1.0f / 16.0f);
    float sq = 0.f;
#pragma unroll
    for (int i = 0; i < 16; ++i) { float d = v[i] - m; sq += d * d; }
    float rs = rsqrtf(sq * (1.0f / 16.0f) + EPSV);
    if (!sel) {
        short* op = kout + (size_t)h * (NR * HDIM) + (size_t)nr * HDIM;
#pragma unroll
        for (int i = 0; i < 16; ++i)
            op[i] = f2b(((v[i] - m) * rs * g[i] + bb[i]) * QK_L2E);
        return;
    }
    int nr_l = t >> 3;               // 0..31  (h = t&7)
#pragma unroll
    for (int i = 0; i < 16; ++i)
        vlds[h][i][nr_l] = (v[i] - m) * rs * g[i] + bb[i];
    __syncthreads();
    int row = t >> 1, half = t & 1;  // 128 rows = (h2,i2); 2 threads/row
    int h2 = row >> 4, i2 = row & 15;
    const float* src = &vlds[h2][i2][half * 16];
    uint4 u0 = {pk2(src[0], src[1]), pk2(src[2], src[3]), pk2(src[4], src[5]), pk2(src[6], src[7])};
    uint4 u1 = {pk2(src[8], src[9]), pk2(src[10], src[11]), pk2(src[12], src[13]), pk2(src[14], src[15])};
    short* dst = vout + (size_t)h2 * (HDIM * NR) + (size_t)i2 * NR + b * 32 + half * 16;
    *(uint4*)(dst)     = u0;
    *(uint4*)(dst + 8) = u1;
}

// ---------------- global attention v8: 8 waves, split-K wave pairs ----------------
__global__ __launch_bounds__(512) void gattn_k(const short* __restrict__ qkv,
                                               const short* __restrict__ kb,   // [8][1024][16] *0.25*log2e
                                               const short* __restrict__ vt,   // [8][16][1024]
                                               short* __restrict__ ob) {
    __shared__ short plds[8][2048];
    __shared__ float comb[4][64][5];
    int t = threadIdx.x;
    int w = t >> 6, l = t & 63;
    int h = blockIdx.y;
    int lr = l & 15, lq = l >> 4;
    int qw = w & 3, kw = w >> 2;
    int q0 = blockIdx.x * 64 + qw * 16;

    short8 qf = short8{0, 0, 0, 0, 0, 0, 0, 0};
    if (lq < 2)
        qf = *(const short8*)(qkv + (size_t)(q0 + lr) * 384 + h * HDIM + lq * 8);

    const short* kh = kb + (size_t)h * (NR * HDIM);
    const short* vh = vt + (size_t)h * (HDIM * NR);
    short* pw = &plds[w][0];

    const f32x4 zz = {0.f, 0.f, 0.f, 0.f};
    f32x4 oacc = {0.f, 0.f, 0.f, 0.f};
    float rs = 0.f;

    for (int c = 0; c < 4; ++c) {
        int kbase = kw * 512 + c * 128;
        f32x4 s[8];
#pragma unroll
        for (int nf = 0; nf < 8; ++nf) {
            short8 kf = short8{0, 0, 0, 0, 0, 0, 0, 0};
            if (lq < 2)
                kf = *(const short8*)(kh + (size_t)(kbase + nf * 16 + lr) * HDIM + lq * 8);
            s[nf] = __builtin_amdgcn_mfma_f32_16x16x32_bf16(kf, qf, zz, 0, 0, 0);
        }
#pragma unroll
        for (int nf = 0; nf < 8; ++nf) {
            float p0 = exp2f(s[nf][0]);
            float p1 = exp2f(s[nf][1]);
            float p2 = exp2f(s[nf][2]);
            float p3 = exp2f(s[nf][3]);
            rs += (p0 + p1) + (p2 + p3);
            unsigned int u01, u23;
            asm("v_cvt_pk_bf16_f32 %0, %1, %2" : "=v"(u01) : "v"(p0), "v"(p1));
            asm("v_cvt_pk_bf16_f32 %0, %1, %2" : "=v"(u23) : "v"(p2), "v"(p3));
            int k0 = nf * 16 + lq * 4;
            int sw = (lr & 7) << 3;
            *(unsigned int*)&pw[lr * 128 + (k0 ^ sw)]       = u01;
            *(unsigned int*)&pw[lr * 128 + ((k0 + 2) ^ sw)] = u23;
        }
#pragma unroll
        for (int ks = 0; ks < 4; ++ks) {
            short8 pf = *(const short8*)&pw[(lr * 128 + ks * 32 + lq * 8) ^ ((lr & 7) << 3)];
            short8 vf = *(const short8*)(vh + (size_t)lr * NR + kbase + ks * 32 + lq * 8);
            oacc = __builtin_amdgcn_mfma_f32_16x16x32_bf16(pf, vf, oacc, 0, 0, 0);
        }
    }
    rs += __shfl_xor(rs, 16);
    rs += __shfl_xor(rs, 32);
    if (w >= 4) {
        comb[w - 4][l][0] = oacc[0];
        comb[w - 4][l][1] = oacc[1];
        comb[w - 4][l][2] = oacc[2];
        comb[w - 4][l][3] = oacc[3];
        comb[w - 4][l][4] = rs;
    }
    __syncthreads();
    if (w < 4) {
        oacc[0] += comb[w][l][0];
        oacc[1] += comb[w][l][1];
        oacc[2] += comb[w][l][2];
        oacc[3] += comb[w][l][3];
        rs += comb[w][l][4];
        float r0 = __shfl(rs, lq * 4 + 0);
        float r1 = __shfl(rs, lq * 4 + 1);
        float r2 = __shfl(rs, lq * 4 + 2);
        float r3 = __shfl(rs, lq * 4 + 3);
        size_t base_o = (size_t)(q0 + lq * 4) * C_DIM + h * HDIM + lr;
        ob[base_o]             = f2b(oacc[0] / r0);
        ob[base_o + C_DIM]     = f2b(oacc[1] / r1);
        ob[base_o + 2 * C_DIM] = f2b(oacc[2] / r2);
        ob[base_o + 3 * C_DIM] = f2b(oacc[3] / r3);
    }
}

// ---------------- final gate: out(C,N) = x * sigmoid(loc + glo) ----------------
__global__ __launch_bounds__(256) void gate_k(const float* __restrict__ x,
                                              const float* __restrict__ lf, const float* __restrict__ gf,
                                              float* __restrict__ out) {
    __shared__ float tile[32][33];
    int n0 = blockIdx.x * 32, c0 = blockIdx.y * 32;
    int tx = threadIdx.x, ty = threadIdx.y;
#pragma unroll
    for (int k = 0; k < 4; ++k) {
        int n = n0 + ty + k * 8, c = c0 + tx;
        tile[ty + k * 8][tx] = lf[(size_t)n * C_DIM + c] + gf[(size_t)n * C_DIM + c];
    }
    __syncthreads();
#pragma unroll
    for (int k = 0; k < 4; ++k) {
        int c = c0 + ty + k * 8, n = n0 + tx;
        float z = tile[tx][ty + k * 8];
        float sg = 1.0f / (1.0f + __expf(-z));
        out[(size_t)c * N_TOK + n] = x[(size_t)c * N_TOK + n] * sg;
    }
}

extern "C" void kernel_launch(void* const* d_in, const int* in_sizes, int n_in,
                              void* d_out, int out_size, void* d_ws, size_t ws_size,
                              hipStream_t stream) {
    const float* x        = (const float*)d_in[0];
    const float* l_n1_g   = (const float*)d_in[1];
    const float* l_n1_b   = (const float*)d_in[2];
    const float* l_qkv_w  = (const float*)d_in[3];
    const float* l_proj_w = (const float*)d_in[4];
    const float* l_proj_b = (const float*)d_in[5];
    const float* l_n2_g   = (const float*)d_in[6];
    const float* l_n2_b   = (const float*)d_in[7];
    const float* l_fc1_w  = (const float*)d_in[8];
    const float* l_fc1_b  = (const float*)d_in[9];
    const float* l_fc2_w  = (const float*)d_in[10];
    const float* l_fc2_b  = (const float*)d_in[11];
    const float* g_n1_g   = (const float*)d_in[12];
    const float* g_n1_b   = (const float*)d_in[13];
    const float* g_qkv_w  = (const float*)d_in[14];
    const float* g_proj_w = (const float*)d_in[15];
    const float* g_proj_b = (const float*)d_in[16];
    const float* g_n2_g   = (const float*)d_in[17];
    const float* g_n2_b   = (const float*)d_in[18];
    const float* g_fc1_w  = (const float*)d_in[19];
    const float* g_fc1_b  = (const float*)d_in[20];
    const float* g_fc2_w  = (const float*)d_in[21];
    const float* g_fc2_b  = (const float*)d_in[22];
    const float* g_ke_w   = (const float*)d_in[23];
    const float* g_ve_w   = (const float*)d_in[24];
    const float* g_nk_g   = (const float*)d_in[25];
    const float* g_nk_b   = (const float*)d_in[26];
    const float* g_nv_g   = (const float*)d_in[27];
    const float* g_nv_b   = (const float*)d_in[28];
    float* out = (float*)d_out;

    char* base = (char*)d_ws;
    float* xt     = (float*)(base);                        // 0-4 MB
    float* t1_l   = (float*)(base + (4ull  << 20));        // 4-8 MB
    float* t1_g   = (float*)(base + (8ull  << 20));        // 8-12 MB
    short* yA16   = (short*)(base + (12ull << 20));        // 12-14 (later t2_l)
    short* yG16   = (short*)(base + (14ull << 20));        // 14-16 (later t2_g)
    short* t2_l   = yA16;
    short* t2_g   = yG16;
    float* locfin = (float*)(base + (12ull << 20));        // 12-16 (after fc1 reads t2)
    short* obuf_l = (short*)(base + (16ull << 20));        // 16-18
    short* obuf_g = (short*)(base + (18ull << 20));        // 18-20
    float* glofin = (float*)(base + (16ull << 20));        // 16-20 (after proj reads obuf)
    short* qkv_l  = (short*)(base + (20ull << 20));        // 20-26
    short* qkv_g  = (short*)(base + (26ull << 20));        // 26-32
    short* h1_l   = (short*)(base + (32ull << 20));        // 32-40 (after ln_head)
    float* kpart  = (float*)(base + (32ull << 20));        // 32-36 (pre-fc1)
    float* vpart  = (float*)(base + (36ull << 20));        // 36-40 (pre-fc1)
    short* h1_g   = (short*)(base + (40ull << 20));        // 40-48
    short* kb16   = (short*)(base + (48ull << 20));        // [8][1024][16]
    short* vt16   = (short*)(base + (48ull << 20) + (512ull << 10)); // [8][16][1024]
    short* wts    = (short*)(base + (49ull << 20));        // ~1.3 MB

    const int L_QKV = 0,      L_PROJ = 49152, L_FC1 = 65536,  L_FC2 = 131072;
    const int G_QKV = 196608, G_PROJ = 245760, G_FC1 = 262144, G_FC2 = 327680;
    const int G_KE  = 393216, G_VE   = 524288;

    CvtArgs ca;
    ca.d[0] = {l_qkv_w,  wts + L_QKV,  49152, 0};
    ca.d[1] = {l_proj_w, wts + L_PROJ, 16384, 0};
    ca.d[2] = {l_fc1_w,  wts + L_FC1,  65536, 0};
    ca.d[3] = {l_fc2_w,  wts + L_FC2,  65536, 0};
    ca.d[4] = {g_qkv_w,  wts + G_QKV,  49152, 0};
    ca.d[5] = {g_proj_w, wts + G_PROJ, 16384, 0};
    ca.d[6] = {g_fc1_w,  wts + G_FC1,  65536, 0};
    ca.d[7] = {g_fc2_w,  wts + G_FC2,  65536, 0};
    ca.d[8] = {g_ke_w,   wts + G_KE,  131072, 1};   // permuted: [co][off*128+ci]
    ca.d[9] = {g_ve_w,   wts + G_VE,  131072, 1};

    // 1: transpose + LN1 + weight cvt (fused)
    prep_k<<<296, 256, 0, stream>>>(x, l_n1_g, l_n1_b, g_n1_g, g_n1_b, xt, yA16, yG16, ca);

    // 2: both qkv GEMMs
    MArgs a_qkv = {{yA16, yG16}, {wts + L_QKV, wts + G_QKV}, {nullptr, nullptr}, {nullptr, nullptr}, {qkv_l, qkv_g}};
    mgemm_k<0><<<dim3(64, 3, 2), 256, 0, stream>>>(a_qkv, N_TOK, 384, 128);

    // 3: conv reductions (inline gather, split-K x8, async-staged) + local attention
    CLArgs cla = {qkv_g, wts + G_KE, wts + G_VE, kpart, vpart, qkv_l, obuf_l};
    convlat_k<<<384, 256, 0, stream>>>(cla);

    // 4: head-LN for K (scaled for exp2) and V^T (coalesced via LDS transpose)
    ln_head_sum_k<<<64, 256, 0, stream>>>(kpart, vpart, g_nk_g, g_nk_b, g_nv_g, g_nv_b, kb16, vt16);

    // 5: global attention (MFMA flash v8)
    gattn_k<<<dim3(128, 8), 512, 0, stream>>>(qkv_g, kb16, vt16, obuf_g);

    // 6: both proj GEMMs (+bias+residual)
    MArgs a_pj = {{obuf_l, obuf_g}, {wts + L_PROJ, wts + G_PROJ}, {l_proj_b, g_proj_b}, {xt, xt}, {t1_l, t1_g}};
    mgemm_k<1><<<dim3(64, 1, 2), 256, 0, stream>>>(a_pj, N_TOK, 128, 128);

    // 7: both second LNs
    ln2_pair_k<<<4096, 256, 0, stream>>>(t1_l, l_n2_g, l_n2_b, t2_l, t1_g, g_n2_g, g_n2_b, t2_g);

    // 8: both fc1 GEMMs (+bias+gelu)
    MArgs a_f1 = {{t2_l, t2_g}, {wts + L_FC1, wts + G_FC1}, {l_fc1_b, g_fc1_b}, {nullptr, nullptr}, {h1_l, h1_g}};
    mgemm_k<2><<<dim3(64, 4, 2), 256, 0, stream>>>(a_f1, N_TOK, 512, 128);

    // 9: both fc2 GEMMs (+bias+residual)
    MArgs a_f2 = {{h1_l, h1_g}, {wts + L_FC2, wts + G_FC2}, {l_fc2_b, g_fc2_b}, {t1_l, t1_g}, {locfin, glofin}};
    mgemm_k<1><<<dim3(64, 1, 2), 256, 0, stream>>>(a_f2, N_TOK, 128, 512);

    // 10: gate
    gate_k<<<dim3(256, 4), dim3(32, 8), 0, stream>>>(x, locfin, glofin, out);
}